// Round 1
// baseline (650.360 us; speedup 1.0000x reference)
//
#include <hip/hip_runtime.h>
#include <math.h>

// GSS block on MI355X. Shapes: B=2, L=4096, DIM=1024, HID=4096, H=DSSH=512, N=DSSN=512.
// Pipeline: transpose-convert weights -> LN1 -> GEMM(xg) -> GEMM(xd) -> LN2 ->
//           S/C gen -> GEMM(K) -> FFT conv (+D*xn) -> GEMM(gate)*xg -> GEMM(out)+bias+idx.
// Workspace requirement ~158 MB.

typedef unsigned short u16;
typedef unsigned int u32;
typedef __attribute__((ext_vector_type(8))) __bf16 bf16x8;
typedef __attribute__((ext_vector_type(4))) float f32x4;

__device__ __forceinline__ u16 f2bf(float f) {
  u32 u = __float_as_uint(f);
  u32 r = u + 0x7FFFu + ((u >> 16) & 1u);
  return (u16)(r >> 16);
}
__device__ __forceinline__ float bf2f(u16 h) { return __uint_as_float(((u32)h) << 16); }

// ---------------------------------------------------------------- transpose+convert
// in: f32 [K][N] row-major -> out: bf16 [N][K] row-major
__global__ __launch_bounds__(256) void trans_conv(
    const float* __restrict__ in, u16* __restrict__ out, int K, int N) {
  __shared__ float t[32][33];
  int tx = threadIdx.x & 31, ty = threadIdx.x >> 5;
  int nb = N >> 5;
  int k0 = (blockIdx.x / nb) << 5;
  int n0 = (blockIdx.x % nb) << 5;
#pragma unroll
  for (int i = 0; i < 32; i += 8)
    t[ty + i][tx] = in[(size_t)(k0 + ty + i) * N + n0 + tx];
  __syncthreads();
#pragma unroll
  for (int i = 0; i < 32; i += 8)
    out[(size_t)(n0 + ty + i) * K + k0 + tx] = f2bf(t[tx][ty + i]);
}

// ---------------------------------------------------------------- LayerNorm
// one block per row, blockDim = D/4. BOUT: true -> bf16 out, false -> f32 out.
template <bool BOUT>
__global__ void ln_kernel(const float* __restrict__ in, const float* __restrict__ gw,
                          const float* __restrict__ gb, void* outp, int D) {
  int row = blockIdx.x;
  int tid = threadIdx.x;
  const float4* r4 = (const float4*)(in + (size_t)row * D);
  float4 v = r4[tid];
  float s = v.x + v.y + v.z + v.w;
  float ss = fmaf(v.x, v.x, fmaf(v.y, v.y, fmaf(v.z, v.z, v.w * v.w)));
#pragma unroll
  for (int o = 32; o >= 1; o >>= 1) { s += __shfl_xor(s, o); ss += __shfl_xor(ss, o); }
  __shared__ float sa[8], sb[8];
  int nw = blockDim.x >> 6;
  if ((tid & 63) == 0) { sa[tid >> 6] = s; sb[tid >> 6] = ss; }
  __syncthreads();
  float S = 0.f, SS = 0.f;
  for (int i = 0; i < nw; ++i) { S += sa[i]; SS += sb[i]; }
  float mean = S / (float)D;
  float var = SS / (float)D - mean * mean;
  float inv = rsqrtf(var + 1e-5f);
  float4 wv = ((const float4*)gw)[tid];
  float4 bv = ((const float4*)gb)[tid];
  float o0 = (v.x - mean) * inv * wv.x + bv.x;
  float o1 = (v.y - mean) * inv * wv.y + bv.y;
  float o2 = (v.z - mean) * inv * wv.z + bv.z;
  float o3 = (v.w - mean) * inv * wv.w + bv.w;
  if (BOUT) {
    ushort4 o; o.x = f2bf(o0); o.y = f2bf(o1); o.z = f2bf(o2); o.w = f2bf(o3);
    ((ushort4*)outp)[(size_t)row * (D >> 2) + tid] = o;
  } else {
    float4 o; o.x = o0; o.y = o1; o.z = o2; o.w = o3;
    ((float4*)outp)[(size_t)row * (D >> 2) + tid] = o;
  }
}

// ---------------------------------------------------------------- MFMA GEMM
// C[M,N] = A[M,K] @ Bt[N,K]^T, all bf16 in, f32 acc. 128x128 tile, BK=32, 4 waves.
// MODE 0: Cf=f32   1: Cb=bf16   2: Cb=bf16(C*aux)   3: Cf=C+bias[n]+res[m,n]
template <int MODE>
__global__ __launch_bounds__(256) void gemm_bf16(
    const u16* __restrict__ A, const u16* __restrict__ Bt,
    int M, int N, int K,
    float* Cf, u16* Cb, const u16* aux,
    const float* __restrict__ bias, const float* __restrict__ res) {
  __shared__ __align__(16) u16 As[128 * 32];
  __shared__ __align__(16) u16 Bs[128 * 32];
  const int tid = threadIdx.x;
  const int lane = tid & 63;
  const int wid = tid >> 6;
  const int tiles_n = N >> 7;
  const int tm = (int)(blockIdx.x / tiles_n) << 7;
  const int tn = (int)(blockIdx.x % tiles_n) << 7;

  // staging addresses: wave wid covers tile rows [wid*32, wid*32+32) in 2 calls of 16 rows
  const int srow = wid * 32 + (lane >> 2);
  const int scol = (lane & 3) << 3;
  const u16* gA = A + (size_t)(tm + srow) * K + scol;
  const u16* gB = Bt + (size_t)(tn + srow) * K + scol;
  const u16* gA2 = gA + (size_t)16 * K;
  const u16* gB2 = gB + (size_t)16 * K;
  auto As3 = (__attribute__((address_space(3))) char*)As;
  auto Bs3 = (__attribute__((address_space(3))) char*)Bs;
  const u32 lds0 = (u32)wid * 2048u;
  const u32 lds1 = lds0 + 1024u;

  const int lr = lane & 15;
  const int kq = lane >> 4;
  const int wr = (wid >> 1) * 64;
  const int wc = (wid & 1) * 64;

  f32x4 acc[4][4] = {};

  for (int k0 = 0; k0 < K; k0 += 32) {
    __builtin_amdgcn_global_load_lds((const __attribute__((address_space(1))) void*)(gA + k0),
                                     (__attribute__((address_space(3))) void*)(As3 + lds0), 16, 0, 0);
    __builtin_amdgcn_global_load_lds((const __attribute__((address_space(1))) void*)(gA2 + k0),
                                     (__attribute__((address_space(3))) void*)(As3 + lds1), 16, 0, 0);
    __builtin_amdgcn_global_load_lds((const __attribute__((address_space(1))) void*)(gB + k0),
                                     (__attribute__((address_space(3))) void*)(Bs3 + lds0), 16, 0, 0);
    __builtin_amdgcn_global_load_lds((const __attribute__((address_space(1))) void*)(gB2 + k0),
                                     (__attribute__((address_space(3))) void*)(Bs3 + lds1), 16, 0, 0);
    __syncthreads();
    bf16x8 af[4], bfr[4];
#pragma unroll
    for (int mi = 0; mi < 4; ++mi)
      af[mi] = *(const bf16x8*)(As + (wr + mi * 16 + lr) * 32 + kq * 8);
#pragma unroll
    for (int ni = 0; ni < 4; ++ni)
      bfr[ni] = *(const bf16x8*)(Bs + (wc + ni * 16 + lr) * 32 + kq * 8);
#pragma unroll
    for (int mi = 0; mi < 4; ++mi)
#pragma unroll
      for (int ni = 0; ni < 4; ++ni)
        acc[mi][ni] = __builtin_amdgcn_mfma_f32_16x16x32_bf16(af[mi], bfr[ni], acc[mi][ni], 0, 0, 0);
    __syncthreads();
  }

  const int orow = tm + wr + kq * 4;
  const int ocol = tn + wc + lr;
#pragma unroll
  for (int mi = 0; mi < 4; ++mi)
#pragma unroll
    for (int ni = 0; ni < 4; ++ni)
#pragma unroll
      for (int j = 0; j < 4; ++j) {
        int r = orow + mi * 16 + j;
        int c = ocol + ni * 16;
        size_t off = (size_t)r * N + c;
        float v = acc[mi][ni][j];
        if (MODE == 0) Cf[off] = v;
        else if (MODE == 1) Cb[off] = f2bf(v);
        else if (MODE == 2) Cb[off] = f2bf(v * bf2f(aux[off]));
        else Cf[off] = v + bias[c] + res[off];
      }
}

// ---------------------------------------------------------------- DSS kernel generation
// SRSI: bf16 [L=4096][1024]; col<512 -> Re exp(Lam_n * l), col>=512 -> Im exp(Lam_n * l)
__global__ __launch_bounds__(256) void kgen_s(
    const float* __restrict__ LR, const float* __restrict__ LI, u16* __restrict__ SRSI) {
  int idx0 = blockIdx.x * 256 + threadIdx.x;
  int l = idx0 >> 10;
  int kk = idx0 & 1023;
  int n = kk & 511;
  double a = exp((double)LR[n]);
  double om = exp((double)LI[n]);
  double ld = (double)l;
  float decay = (float)exp(-a * ld);
  double th = fmod(om * ld, 6.283185307179586477);
  float c, s;
  sincosf((float)th, &s, &c);
  SRSI[idx0] = f2bf(decay * ((kk < 512) ? c : s));
}

// Ct: bf16 [H=512][1024]; col<512 -> CcR[h,col], col>=512 -> -CcI[h,col-512]
__global__ __launch_bounds__(256) void kgen_c(
    const float* __restrict__ LR, const float* __restrict__ LI,
    const float* __restrict__ CR, const float* __restrict__ CI, u16* __restrict__ Ct) {
  int idx0 = blockIdx.x * 256 + threadIdx.x;  // over 512*512
  int h = idx0 >> 9, n = idx0 & 511;
  float eLR = expf(LR[n]), eLI = expf(LI[n]);
  float lre = -eLR, lim = eLI;
  float er = expf(lre);
  float c, s;
  sincosf(lim, &s, &c);
  float wr = er * c - 1.0f, wi = er * s;   // exp(Lam) - 1
  float den = lre * lre + lim * lim;
  float gr = (wr * lre + wi * lim) / den;  // (exp(Lam)-1)/Lam
  float gi = (wi * lre - wr * lim) / den;
  float cr = CR[(size_t)h * 512 + n], ci = CI[(size_t)h * 512 + n];
  float ccr = cr * gr - ci * gi;
  float cci = cr * gi + ci * gr;
  Ct[(size_t)h * 1024 + n] = f2bf(ccr);
  Ct[(size_t)h * 1024 + 512 + n] = f2bf(-cci);
}

// ---------------------------------------------------------------- FFT convolution
#define FFTN 8192
#define FFTLOG 13

__device__ __forceinline__ void fft8192(float* zr, float* zi, int tid) {
#pragma unroll
  for (int s = 0; s < FFTLOG; ++s) {
    int m = 1 << s;
#pragma unroll
    for (int it = 0; it < 8; ++it) {
      int t = tid + it * 512;
      int pos = t & (m - 1);
      int i0 = ((t >> s) << (s + 1)) + pos;
      int i1 = i0 + m;
      float ang = -3.14159265358979f * (float)pos / (float)m;
      float c, sn;
      sincosf(ang, &sn, &c);
      float ar = zr[i0], ai = zi[i0];
      float br = zr[i1], bi = zi[i1];
      float tr = br * c - bi * sn;
      float ti = br * sn + bi * c;
      zr[i0] = ar + tr; zi[i0] = ai + ti;
      zr[i1] = ar - tr; zi[i1] = ai - ti;
    }
    __syncthreads();
  }
}

// per (b,h): z = xn[b,:,h] + i*K[:,h] (zero-pad 4096->8192), Z=FFT(z),
// split hermitian halves -> P = X*Kf, second forward FFT of conj(P) -> y = Re(.)/N,
// d = y + D[h]*xn. One workgroup per (b,h). 64 KB LDS.
__global__ __launch_bounds__(512) void fft_conv(
    const float* __restrict__ xn, const float* __restrict__ Km,
    const float* __restrict__ Dv, u16* dout, int Hc, int L) {
  __shared__ float zr[FFTN];
  __shared__ float zi[FFTN];
  int b = blockIdx.x / Hc, h = blockIdx.x % Hc;
  int tid = threadIdx.x;
  const float* xcol = xn + ((size_t)b * L) * Hc + h;
  const float* kcol = Km + h;
#pragma unroll
  for (int it = 0; it < 16; ++it) {
    int j = tid + it * 512;
    int l = __brev((u32)j) >> (32 - FFTLOG);
    float xv = 0.f, kv = 0.f;
    if (l < L) { xv = xcol[(size_t)l * Hc]; kv = kcol[(size_t)l * Hc]; }
    zr[j] = xv; zi[j] = kv;
  }
  __syncthreads();
  fft8192(zr, zi, tid);
  float prv[16], piv[16];
#pragma unroll
  for (int it = 0; it < 16; ++it) {
    int j = tid + it * 512;
    int k = __brev((u32)j) >> (32 - FFTLOG);
    int km = (FFTN - k) & (FFTN - 1);
    float ar = zr[k], ai = zi[k];
    float br = zr[km], bi = zi[km];
    float xr = 0.5f * (ar + br), xi2 = 0.5f * (ai - bi);   // X = (Z[k]+conj(Z[-k]))/2
    float kr = 0.5f * (ai + bi), ki = 0.5f * (br - ar);    // Kf = (Z[k]-conj(Z[-k]))/(2i)
    prv[it] = xr * kr - xi2 * ki;
    piv[it] = -(xr * ki + xi2 * kr);                        // conj(P)
  }
  __syncthreads();
#pragma unroll
  for (int it = 0; it < 16; ++it) { int j = tid + it * 512; zr[j] = prv[it]; zi[j] = piv[it]; }
  __syncthreads();
  fft8192(zr, zi, tid);
  float Dh = Dv[h];
  u16* dcol = dout + ((size_t)b * L) * Hc + h;
  const float scale = 1.0f / (float)FFTN;
#pragma unroll
  for (int it = 0; it < 8; ++it) {
    int n = tid + it * 512;
    float y = zr[n] * scale;
    float dv = y + Dh * xcol[(size_t)n * Hc];
    dcol[(size_t)n * Hc] = f2bf(dv);
  }
}

// ---------------------------------------------------------------- launch
extern "C" void kernel_launch(void* const* d_in, const int* in_sizes, int n_in,
                              void* d_out, int out_size, void* d_ws, size_t ws_size,
                              hipStream_t stream) {
  (void)in_sizes; (void)n_in; (void)out_size; (void)ws_size;
  const float* idx  = (const float*)d_in[0];
  const float* n1w  = (const float*)d_in[1];
  const float* n1b  = (const float*)d_in[2];
  const float* Wxg  = (const float*)d_in[3];
  const float* Wdin = (const float*)d_in[4];
  const float* n2w  = (const float*)d_in[5];
  const float* n2b  = (const float*)d_in[6];
  const float* LR   = (const float*)d_in[7];
  const float* LI   = (const float*)d_in[8];
  const float* CR   = (const float*)d_in[9];
  const float* CI   = (const float*)d_in[10];
  const float* Dv   = (const float*)d_in[11];
  const float* Wgate= (const float*)d_in[12];
  const float* Wout = (const float*)d_in[13];
  const float* bout = (const float*)d_in[14];
  float* out = (float*)d_out;

  const int Bn = 2, L = 4096, DIM = 1024, HID = 4096, H = 512;
  const int M = Bn * L;  // 8192

  char* p = (char*)d_ws;
  auto alloc = [&](size_t bytes) { char* q = p; p += (bytes + 255) & ~(size_t)255; return q; };
  u16* Wxg_t  = (u16*)alloc((size_t)HID * DIM * 2);   // [4096][1024]
  u16* Wdin_t = (u16*)alloc((size_t)H * DIM * 2);     // [512][1024]
  u16* Wgate_t= (u16*)alloc((size_t)HID * H * 2);     // [4096][512]
  u16* Wout_t = (u16*)alloc((size_t)DIM * HID * 2);   // [1024][4096]
  u16* xbf    = (u16*)alloc((size_t)M * DIM * 2);     // LN1 out bf16
  u16* xg     = (u16*)alloc((size_t)M * HID * 2);     // xg bf16; later aliased as e
  float* xd   = (float*)alloc((size_t)M * H * 4);
  float* xnb  = (float*)alloc((size_t)M * H * 4);
  u16* SRSI   = (u16*)alloc((size_t)L * 1024 * 2);
  u16* Ct     = (u16*)alloc((size_t)H * 1024 * 2);
  float* Kmat = (float*)alloc((size_t)L * H * 4);
  u16* dbuf   = (u16*)alloc((size_t)M * H * 2);

  // 1) weight transpose+convert
  trans_conv<<<dim3((DIM / 32) * (HID / 32)), 256, 0, stream>>>(Wxg, Wxg_t, DIM, HID);
  trans_conv<<<dim3((DIM / 32) * (H / 32)), 256, 0, stream>>>(Wdin, Wdin_t, DIM, H);
  trans_conv<<<dim3((H / 32) * (HID / 32)), 256, 0, stream>>>(Wgate, Wgate_t, H, HID);
  trans_conv<<<dim3((HID / 32) * (DIM / 32)), 256, 0, stream>>>(Wout, Wout_t, HID, DIM);
  // 2) LN1
  ln_kernel<true><<<dim3(M), 256, 0, stream>>>(idx, n1w, n1b, xbf, DIM);
  // 3) xg = x @ Wxg (bf16 out)
  gemm_bf16<1><<<dim3((M / 128) * (HID / 128)), 256, 0, stream>>>(
      xbf, Wxg_t, M, HID, DIM, nullptr, xg, nullptr, nullptr, nullptr);
  // 4) xd = x @ Wdin (f32 out)
  gemm_bf16<0><<<dim3((M / 128) * (H / 128)), 256, 0, stream>>>(
      xbf, Wdin_t, M, H, DIM, xd, nullptr, nullptr, nullptr, nullptr);
  // 5) LN2
  ln_kernel<false><<<dim3(M), 128, 0, stream>>>(xd, n2w, n2b, xnb, H);
  // 6) S and C generation
  kgen_s<<<dim3(L * 1024 / 256), 256, 0, stream>>>(LR, LI, SRSI);
  kgen_c<<<dim3(H * 512 / 256), 256, 0, stream>>>(LR, LI, CR, CI, Ct);
  // 7) K = SR@CcR^T - SI@CcI^T  (single fused bf16 GEMM, f32 out)
  gemm_bf16<0><<<dim3((L / 128) * (H / 128)), 256, 0, stream>>>(
      SRSI, Ct, L, H, 1024, Kmat, nullptr, nullptr, nullptr, nullptr);
  // 8) FFT causal conv + D*xn -> d (bf16)
  fft_conv<<<dim3(Bn * H), 512, 0, stream>>>(xnb, Kmat, Dv, dbuf, H, L);
  // 9) e = (d @ Wgate) * xg  (bf16 out, aliases xg buffer: per-element read-then-write)
  gemm_bf16<2><<<dim3((M / 128) * (HID / 128)), 256, 0, stream>>>(
      dbuf, Wgate_t, M, HID, H, nullptr, xg, xg, nullptr, nullptr);
  // 10) out = e @ Wout + bout + idx  (f32)
  gemm_bf16<3><<<dim3((M / 128) * (DIM / 128)), 256, 0, stream>>>(
      xg, Wout_t, M, DIM, HID, out, nullptr, nullptr, bout, idx);
}

// Round 2
// 472.618 us; speedup vs baseline: 1.3761x; 1.3761x over previous
//
#include <hip/hip_runtime.h>
#include <math.h>

// GSS block on MI355X. Shapes: B=2, L=4096, DIM=1024, HID=4096, H=DSSH=512, N=DSSN=512.
// R2: FFT conv rewritten: transposed dataflow (contiguous rows), DIF->pair->DIT,
// fused radix-4 LDS passes + register radix-8, float2 LDS with XOR bank swizzle,
// hardware v_sin/v_cos twiddles. GEMMs get XCD-aware block swizzle.

typedef unsigned short u16;
typedef unsigned int u32;
typedef __attribute__((ext_vector_type(8))) __bf16 bf16x8;
typedef __attribute__((ext_vector_type(4))) float f32x4;

__device__ __forceinline__ u16 f2bf(float f) {
  u32 u = __float_as_uint(f);
  u32 r = u + 0x7FFFu + ((u >> 16) & 1u);
  return (u16)(r >> 16);
}
__device__ __forceinline__ float bf2f(u16 h) { return __uint_as_float(((u32)h) << 16); }

// ---------------------------------------------------------------- transpose+convert
__global__ __launch_bounds__(256) void trans_conv(
    const float* __restrict__ in, u16* __restrict__ out, int K, int N) {
  __shared__ float t[32][33];
  int tx = threadIdx.x & 31, ty = threadIdx.x >> 5;
  int nb = N >> 5;
  int k0 = (blockIdx.x / nb) << 5;
  int n0 = (blockIdx.x % nb) << 5;
#pragma unroll
  for (int i = 0; i < 32; i += 8)
    t[ty + i][tx] = in[(size_t)(k0 + ty + i) * N + n0 + tx];
  __syncthreads();
#pragma unroll
  for (int i = 0; i < 32; i += 8)
    out[(size_t)(n0 + ty + i) * K + k0 + tx] = f2bf(t[tx][ty + i]);
}

// bf16 [R][C] -> bf16 [C][R]
__global__ __launch_bounds__(256) void trans_bf(
    const u16* __restrict__ in, u16* __restrict__ out, int R, int C) {
  __shared__ u16 t[32][34];
  int tx = threadIdx.x & 31, ty = threadIdx.x >> 5;
  int nb = C >> 5;
  int r0 = (blockIdx.x / nb) << 5;
  int c0 = (blockIdx.x % nb) << 5;
#pragma unroll
  for (int i = 0; i < 32; i += 8)
    t[ty + i][tx] = in[(size_t)(r0 + ty + i) * C + c0 + tx];
  __syncthreads();
#pragma unroll
  for (int i = 0; i < 32; i += 8)
    out[(size_t)(c0 + ty + i) * R + r0 + tx] = t[tx][ty + i];
}

// ---------------------------------------------------------------- LayerNorm (LN1)
template <bool BOUT>
__global__ void ln_kernel(const float* __restrict__ in, const float* __restrict__ gw,
                          const float* __restrict__ gb, void* outp, int D) {
  int row = blockIdx.x;
  int tid = threadIdx.x;
  const float4* r4 = (const float4*)(in + (size_t)row * D);
  float4 v = r4[tid];
  float s = v.x + v.y + v.z + v.w;
  float ss = fmaf(v.x, v.x, fmaf(v.y, v.y, fmaf(v.z, v.z, v.w * v.w)));
#pragma unroll
  for (int o = 32; o >= 1; o >>= 1) { s += __shfl_xor(s, o); ss += __shfl_xor(ss, o); }
  __shared__ float sa[8], sb[8];
  int nw = blockDim.x >> 6;
  if ((tid & 63) == 0) { sa[tid >> 6] = s; sb[tid >> 6] = ss; }
  __syncthreads();
  float S = 0.f, SS = 0.f;
  for (int i = 0; i < nw; ++i) { S += sa[i]; SS += sb[i]; }
  float mean = S / (float)D;
  float var = SS / (float)D - mean * mean;
  float inv = rsqrtf(var + 1e-5f);
  float4 wv = ((const float4*)gw)[tid];
  float4 bv = ((const float4*)gb)[tid];
  float o0 = (v.x - mean) * inv * wv.x + bv.x;
  float o1 = (v.y - mean) * inv * wv.y + bv.y;
  float o2 = (v.z - mean) * inv * wv.z + bv.z;
  float o3 = (v.w - mean) * inv * wv.w + bv.w;
  if (BOUT) {
    ushort4 o; o.x = f2bf(o0); o.y = f2bf(o1); o.z = f2bf(o2); o.w = f2bf(o3);
    ((ushort4*)outp)[(size_t)row * (D >> 2) + tid] = o;
  } else {
    float4 o; o.x = o0; o.y = o1; o.z = o2; o.w = o3;
    ((float4*)outp)[(size_t)row * (D >> 2) + tid] = o;
  }
}

// ---------------------------------------------------------------- LN2 column stats
// xdT [512][8192] -> meanv[8192], invv[8192]. 128 blocks x 256 thr; 64 cols/block.
__global__ __launch_bounds__(256) void ln_stats(
    const float* __restrict__ xdT, float* __restrict__ meanv, float* __restrict__ invv) {
  int lane = threadIdx.x & 63;
  int seg = threadIdx.x >> 6;
  int col = blockIdx.x * 64 + lane;
  float s = 0.f, ss = 0.f;
  const float* p = xdT + (size_t)(seg * 128) * 8192 + col;
  for (int r = 0; r < 128; ++r) {
    float v = p[(size_t)r * 8192];
    s += v; ss = fmaf(v, v, ss);
  }
  __shared__ float sa[4][64], sb[4][64];
  sa[seg][lane] = s; sb[seg][lane] = ss;
  __syncthreads();
  if (threadIdx.x < 64) {
    float S = sa[0][lane] + sa[1][lane] + sa[2][lane] + sa[3][lane];
    float SS = sb[0][lane] + sb[1][lane] + sb[2][lane] + sb[3][lane];
    float mean = S * (1.0f / 512.0f);
    float var = SS * (1.0f / 512.0f) - mean * mean;
    meanv[blockIdx.x * 64 + lane] = mean;
    invv[blockIdx.x * 64 + lane] = rsqrtf(var + 1e-5f);
  }
}

// ---------------------------------------------------------------- MFMA GEMM
// C[M,N] = A[M,K] @ Bt[N,K]^T. MODE 0: f32  1: bf16  2: bf16(C*aux)  3: f32 C+bias+res
template <int MODE>
__global__ __launch_bounds__(256) void gemm_bf16(
    const u16* __restrict__ A, const u16* __restrict__ Bt,
    int M, int N, int K,
    float* Cf, u16* Cb, const u16* aux,
    const float* __restrict__ bias, const float* __restrict__ res) {
  __shared__ __align__(16) u16 As[128 * 32];
  __shared__ __align__(16) u16 Bs[128 * 32];
  const int tid = threadIdx.x;
  const int lane = tid & 63;
  const int wid = tid >> 6;
  // XCD-aware bijective block swizzle (all grids here are divisible by 8)
  const int nwg = (int)gridDim.x;
  const int cpx = nwg >> 3;
  const int bid = ((int)blockIdx.x & 7) * cpx + ((int)blockIdx.x >> 3);
  const int tiles_n = N >> 7;
  const int tm = (bid / tiles_n) << 7;
  const int tn = (bid % tiles_n) << 7;

  const int srow = wid * 32 + (lane >> 2);
  const int scol = (lane & 3) << 3;
  const u16* gA = A + (size_t)(tm + srow) * K + scol;
  const u16* gB = Bt + (size_t)(tn + srow) * K + scol;
  const u16* gA2 = gA + (size_t)16 * K;
  const u16* gB2 = gB + (size_t)16 * K;
  auto As3 = (__attribute__((address_space(3))) char*)As;
  auto Bs3 = (__attribute__((address_space(3))) char*)Bs;
  const u32 lds0 = (u32)wid * 2048u;
  const u32 lds1 = lds0 + 1024u;

  const int lr = lane & 15;
  const int kq = lane >> 4;
  const int wr = (wid >> 1) * 64;
  const int wc = (wid & 1) * 64;

  f32x4 acc[4][4] = {};

  for (int k0 = 0; k0 < K; k0 += 32) {
    __builtin_amdgcn_global_load_lds((const __attribute__((address_space(1))) void*)(gA + k0),
                                     (__attribute__((address_space(3))) void*)(As3 + lds0), 16, 0, 0);
    __builtin_amdgcn_global_load_lds((const __attribute__((address_space(1))) void*)(gA2 + k0),
                                     (__attribute__((address_space(3))) void*)(As3 + lds1), 16, 0, 0);
    __builtin_amdgcn_global_load_lds((const __attribute__((address_space(1))) void*)(gB + k0),
                                     (__attribute__((address_space(3))) void*)(Bs3 + lds0), 16, 0, 0);
    __builtin_amdgcn_global_load_lds((const __attribute__((address_space(1))) void*)(gB2 + k0),
                                     (__attribute__((address_space(3))) void*)(Bs3 + lds1), 16, 0, 0);
    __syncthreads();
    bf16x8 af[4], bfr[4];
#pragma unroll
    for (int mi = 0; mi < 4; ++mi)
      af[mi] = *(const bf16x8*)(As + (wr + mi * 16 + lr) * 32 + kq * 8);
#pragma unroll
    for (int ni = 0; ni < 4; ++ni)
      bfr[ni] = *(const bf16x8*)(Bs + (wc + ni * 16 + lr) * 32 + kq * 8);
#pragma unroll
    for (int mi = 0; mi < 4; ++mi)
#pragma unroll
      for (int ni = 0; ni < 4; ++ni)
        acc[mi][ni] = __builtin_amdgcn_mfma_f32_16x16x32_bf16(af[mi], bfr[ni], acc[mi][ni], 0, 0, 0);
    __syncthreads();
  }

  const int orow = tm + wr + kq * 4;
  const int ocol = tn + wc + lr;
#pragma unroll
  for (int mi = 0; mi < 4; ++mi)
#pragma unroll
    for (int ni = 0; ni < 4; ++ni)
#pragma unroll
      for (int j = 0; j < 4; ++j) {
        int r = orow + mi * 16 + j;
        int c = ocol + ni * 16;
        size_t off = (size_t)r * N + c;
        float v = acc[mi][ni][j];
        if (MODE == 0) Cf[off] = v;
        else if (MODE == 1) Cb[off] = f2bf(v);
        else if (MODE == 2) Cb[off] = f2bf(v * bf2f(aux[off]));
        else Cf[off] = v + bias[c] + res[off];
      }
}

// ---------------------------------------------------------------- DSS kernel generation
__global__ __launch_bounds__(256) void kgen_s(
    const float* __restrict__ LR, const float* __restrict__ LI, u16* __restrict__ SRSI) {
  int idx0 = blockIdx.x * 256 + threadIdx.x;
  int l = idx0 >> 10;
  int kk = idx0 & 1023;
  int n = kk & 511;
  double a = exp((double)LR[n]);
  double om = exp((double)LI[n]);
  double ld = (double)l;
  float decay = (float)exp(-a * ld);
  double th = fmod(om * ld, 6.283185307179586477);
  float c, s;
  sincosf((float)th, &s, &c);
  SRSI[idx0] = f2bf(decay * ((kk < 512) ? c : s));
}

__global__ __launch_bounds__(256) void kgen_c(
    const float* __restrict__ LR, const float* __restrict__ LI,
    const float* __restrict__ CR, const float* __restrict__ CI, u16* __restrict__ Ct) {
  int idx0 = blockIdx.x * 256 + threadIdx.x;  // over 512*512
  int h = idx0 >> 9, n = idx0 & 511;
  float eLR = expf(LR[n]), eLI = expf(LI[n]);
  float lre = -eLR, lim = eLI;
  float er = expf(lre);
  float c, s;
  sincosf(lim, &s, &c);
  float wr = er * c - 1.0f, wi = er * s;
  float den = lre * lre + lim * lim;
  float gr = (wr * lre + wi * lim) / den;
  float gi = (wi * lre - wr * lim) / den;
  float cr = CR[(size_t)h * 512 + n], ci = CI[(size_t)h * 512 + n];
  float ccr = cr * gr - ci * gi;
  float cci = cr * gi + ci * gr;
  Ct[(size_t)h * 1024 + n] = f2bf(ccr);
  Ct[(size_t)h * 1024 + 512 + n] = f2bf(-cci);
}

// ---------------------------------------------------------------- FFT convolution v2
struct C2 { float x, y; };
__device__ __forceinline__ C2 cadd(C2 a, C2 b) { return {a.x + b.x, a.y + b.y}; }
__device__ __forceinline__ C2 csub(C2 a, C2 b) { return {a.x - b.x, a.y - b.y}; }
__device__ __forceinline__ C2 cmul(C2 a, C2 b) {
  return {a.x * b.x - a.y * b.y, a.x * b.y + a.y * b.x};
}
__device__ __forceinline__ C2 cmulni(C2 a) { return {a.y, -a.x}; }  // * (-i)

// Bank swizzle for float2 LDS (element index). Bijective (only bits 0..3 XORed
// with a function of bits >=4). Paper-verified minimal (4 lanes/bank-pair) for
// every access family used below.
__device__ __forceinline__ int swz(int a) {
  return a ^ ((a >> 7) & 15) ^ ((a >> 11) & 3) ^ ((a >> 2) & 8) ^ ((a >> 3) & 2) ^ ((a >> 4) & 4);
}

#define BR13(x) ((int)(__brev((u32)(x)) >> 19))

// Fused radix-4 DIF pass = two in-place radix-2 DIF stages (spans 2M, M), M = 1<<LOGM.
template <int LOGM>
__device__ __forceinline__ void dif_pass(C2* z, int tid) {
  const int M4 = 1 << LOGM;
  const float inv4m = 1.0f / (float)(4 * M4);
#pragma unroll
  for (int j = 0; j < 4; ++j) {
    int b = tid + j * 512;
    int pos = b & (M4 - 1);
    int i0 = ((b >> LOGM) << (LOGM + 2)) | pos;
    int ia = swz(i0), ib = swz(i0 + M4), ic = swz(i0 + 2 * M4), id = swz(i0 + 3 * M4);
    C2 a = z[ia], bb = z[ib], c = z[ic], d = z[id];
    float rev = -(float)pos * inv4m;
    float wc = __builtin_amdgcn_cosf(rev);
    float ws = __builtin_amdgcn_sinf(rev);
    C2 w = {wc, ws};
    C2 wm = {ws, -wc};                       // -i * w
    C2 w2 = {wc * wc - ws * ws, 2.f * wc * ws};  // w^2
    C2 a1 = cadd(a, c);
    C2 c1 = cmul(csub(a, c), w);
    C2 b1 = cadd(bb, d);
    C2 d1 = cmul(csub(bb, d), wm);
    z[ia] = cadd(a1, b1);
    z[ib] = cmul(csub(a1, b1), w2);
    z[ic] = cadd(c1, d1);
    z[id] = cmul(csub(c1, d1), w2);
  }
}

// Fused radix-4 DIT pass (spans M, 2M).
template <int LOGM>
__device__ __forceinline__ void dit_pass(C2* z, int tid) {
  const int M4 = 1 << LOGM;
  const float inv4m = 1.0f / (float)(4 * M4);
#pragma unroll
  for (int j = 0; j < 4; ++j) {
    int b = tid + j * 512;
    int pos = b & (M4 - 1);
    int i0 = ((b >> LOGM) << (LOGM + 2)) | pos;
    int ia = swz(i0), ib = swz(i0 + M4), ic = swz(i0 + 2 * M4), id = swz(i0 + 3 * M4);
    C2 a = z[ia], bb = z[ib], c = z[ic], d = z[id];
    float rev = -(float)pos * inv4m;
    float wc = __builtin_amdgcn_cosf(rev);
    float ws = __builtin_amdgcn_sinf(rev);
    C2 w = {wc, ws};
    C2 wm = {ws, -wc};
    C2 wa = {wc * wc - ws * ws, 2.f * wc * ws};
    C2 t = cmul(wa, bb);
    C2 a1 = cadd(a, t), b1 = csub(a, t);
    C2 u = cmul(wa, d);
    C2 c1 = cadd(c, u), d1 = csub(c, u);
    C2 v = cmul(w, c1);
    C2 xx = cmul(wm, d1);
    z[ia] = cadd(a1, v);
    z[ic] = csub(a1, v);
    z[ib] = cadd(b1, xx);
    z[id] = csub(b1, xx);
  }
}

#define RS 0.70710678118654752f

// Register radix-8 (DIF: spans 4,2,1 — constant twiddles).
__device__ __forceinline__ void dif_r8(C2* z, int tid) {
#pragma unroll
  for (int j = 0; j < 2; ++j) {
    int base = (tid + j * 512) << 3;
    int ad[8]; C2 x[8];
#pragma unroll
    for (int e = 0; e < 8; ++e) { ad[e] = swz(base + e); x[e] = z[ad[e]]; }
    C2 t;
    // span 4: W8^e
    t = csub(x[0], x[4]); x[0] = cadd(x[0], x[4]); x[4] = t;
    t = csub(x[1], x[5]); x[1] = cadd(x[1], x[5]); x[5] = cmul(t, {RS, -RS});
    t = csub(x[2], x[6]); x[2] = cadd(x[2], x[6]); x[6] = cmulni(t);
    t = csub(x[3], x[7]); x[3] = cadd(x[3], x[7]); x[7] = cmul(t, {-RS, -RS});
    // span 2: W4^{e&1}
    t = csub(x[0], x[2]); x[0] = cadd(x[0], x[2]); x[2] = t;
    t = csub(x[1], x[3]); x[1] = cadd(x[1], x[3]); x[3] = cmulni(t);
    t = csub(x[4], x[6]); x[4] = cadd(x[4], x[6]); x[6] = t;
    t = csub(x[5], x[7]); x[5] = cadd(x[5], x[7]); x[7] = cmulni(t);
    // span 1
    t = csub(x[0], x[1]); x[0] = cadd(x[0], x[1]); x[1] = t;
    t = csub(x[2], x[3]); x[2] = cadd(x[2], x[3]); x[3] = t;
    t = csub(x[4], x[5]); x[4] = cadd(x[4], x[5]); x[5] = t;
    t = csub(x[6], x[7]); x[6] = cadd(x[6], x[7]); x[7] = t;
#pragma unroll
    for (int e = 0; e < 8; ++e) z[ad[e]] = x[e];
  }
}

// Register radix-8 (DIT: spans 1,2,4).
__device__ __forceinline__ void dit_r8(C2* z, int tid) {
#pragma unroll
  for (int j = 0; j < 2; ++j) {
    int base = (tid + j * 512) << 3;
    int ad[8]; C2 x[8];
#pragma unroll
    for (int e = 0; e < 8; ++e) { ad[e] = swz(base + e); x[e] = z[ad[e]]; }
    C2 t;
    // span 1
    t = x[1]; x[1] = csub(x[0], t); x[0] = cadd(x[0], t);
    t = x[3]; x[3] = csub(x[2], t); x[2] = cadd(x[2], t);
    t = x[5]; x[5] = csub(x[4], t); x[4] = cadd(x[4], t);
    t = x[7]; x[7] = csub(x[6], t); x[6] = cadd(x[6], t);
    // span 2: W4^{e&1}
    t = x[2];          x[2] = csub(x[0], t); x[0] = cadd(x[0], t);
    t = cmulni(x[3]);  x[3] = csub(x[1], t); x[1] = cadd(x[1], t);
    t = x[6];          x[6] = csub(x[4], t); x[4] = cadd(x[4], t);
    t = cmulni(x[7]);  x[7] = csub(x[5], t); x[5] = cadd(x[5], t);
    // span 4: W8^e
    t = x[4];                    x[4] = csub(x[0], t); x[0] = cadd(x[0], t);
    t = cmul(x[5], {RS, -RS});   x[5] = csub(x[1], t); x[1] = cadd(x[1], t);
    t = cmulni(x[6]);            x[6] = csub(x[2], t); x[2] = cadd(x[2], t);
    t = cmul(x[7], {-RS, -RS});  x[7] = csub(x[3], t); x[3] = cadd(x[3], t);
#pragma unroll
    for (int e = 0; e < 8; ++e) z[ad[e]] = x[e];
  }
}

// per (b,h): z = LN2(xd^T row) + i*K^T row (zero-pad to 8192); DIF FFT; Hermitian
// split + P = X*Kf (store conj(P) in bit-rev position); DIT FFT; y = Re/8192;
// dT[h][b*L+n] = bf16(y + D[h]*xn).
__global__ __launch_bounds__(512) void fft_conv2(
    const float* __restrict__ xdT, const float* __restrict__ KT,
    const float* __restrict__ meanv, const float* __restrict__ invv,
    const float* __restrict__ n2w, const float* __restrict__ n2b,
    const float* __restrict__ Dv, u16* __restrict__ dT) {
  __shared__ C2 z[8192];
  const int tid = threadIdx.x;
  const int h = blockIdx.x & 511;
  const int b = blockIdx.x >> 9;
  const float* xrow = xdT + ((size_t)h << 13) + (b << 12);
  const float* krow = KT + ((size_t)h << 12);
  const float* mrow = meanv + (b << 12);
  const float* irow = invv + (b << 12);
  const float w2h = n2w[h], b2h = n2b[h], Dh = Dv[h];
  const int l0 = tid << 3;

  float xv[8], kv[8], mv[8], iv[8], xn8[8];
  *(float4*)&xv[0] = *(const float4*)(xrow + l0);
  *(float4*)&xv[4] = *(const float4*)(xrow + l0 + 4);
  *(float4*)&kv[0] = *(const float4*)(krow + l0);
  *(float4*)&kv[4] = *(const float4*)(krow + l0 + 4);
  *(float4*)&mv[0] = *(const float4*)(mrow + l0);
  *(float4*)&mv[4] = *(const float4*)(mrow + l0 + 4);
  *(float4*)&iv[0] = *(const float4*)(irow + l0);
  *(float4*)&iv[4] = *(const float4*)(irow + l0 + 4);
#pragma unroll
  for (int e = 0; e < 8; ++e) {
    xn8[e] = (xv[e] - mv[e]) * iv[e] * w2h + b2h;
    z[swz(l0 + e)] = {xn8[e], kv[e]};
    z[swz(4096 + l0 + e)] = {0.f, 0.f};
  }
  __syncthreads();

  // ---- forward DIF FFT (natural in -> bit-rev out)
  dif_pass<11>(z, tid); __syncthreads();
  dif_pass<9>(z, tid);  __syncthreads();
  dif_pass<7>(z, tid);  __syncthreads();
  dif_pass<5>(z, tid);  __syncthreads();
  dif_pass<3>(z, tid);  __syncthreads();
  dif_r8(z, tid);       __syncthreads();

  // ---- Hermitian split + pointwise product (in bit-rev storage)
  C2 P[16];
#pragma unroll
  for (int it = 0; it < 16; ++it) {
    int p = tid + it * 512;
    int k = BR13(p);
    int km = (8192 - k) & 8191;
    int p2 = BR13(km);
    C2 Zk = z[swz(p)], Zm = z[swz(p2)];
    // factors of 1/2 deferred to final scaling (1/4 total)
    float xr = Zk.x + Zm.x, xi = Zk.y - Zm.y;
    float kr = Zk.y + Zm.y, ki = Zm.x - Zk.x;
    P[it] = {xr * kr - xi * ki, -(xr * ki + xi * kr)};  // conj(X*Kf)*4
  }
  __syncthreads();
#pragma unroll
  for (int it = 0; it < 16; ++it) z[swz(tid + it * 512)] = P[it];
  __syncthreads();

  // ---- inverse via forward DIT FFT of conj(P) (bit-rev in -> natural out)
  dit_r8(z, tid);       __syncthreads();
  dit_pass<3>(z, tid);  __syncthreads();
  dit_pass<5>(z, tid);  __syncthreads();
  dit_pass<7>(z, tid);  __syncthreads();
  dit_pass<9>(z, tid);  __syncthreads();
  dit_pass<11>(z, tid); __syncthreads();

  const float sc = 1.0f / 32768.0f;  // 1/8192 * 1/4
  u16 o[8];
#pragma unroll
  for (int e = 0; e < 8; ++e) {
    float y = z[swz(l0 + e)].x * sc;
    o[e] = f2bf(fmaf(Dh, xn8[e], y));
  }
  uint4 pk;
  pk.x = (u32)o[0] | ((u32)o[1] << 16);
  pk.y = (u32)o[2] | ((u32)o[3] << 16);
  pk.z = (u32)o[4] | ((u32)o[5] << 16);
  pk.w = (u32)o[6] | ((u32)o[7] << 16);
  *(uint4*)(dT + ((size_t)h << 13) + (b << 12) + l0) = pk;
}

// ---------------------------------------------------------------- launch
extern "C" void kernel_launch(void* const* d_in, const int* in_sizes, int n_in,
                              void* d_out, int out_size, void* d_ws, size_t ws_size,
                              hipStream_t stream) {
  (void)in_sizes; (void)n_in; (void)out_size; (void)ws_size;
  const float* idx  = (const float*)d_in[0];
  const float* n1w  = (const float*)d_in[1];
  const float* n1b  = (const float*)d_in[2];
  const float* Wxg  = (const float*)d_in[3];
  const float* Wdin = (const float*)d_in[4];
  const float* n2w  = (const float*)d_in[5];
  const float* n2b  = (const float*)d_in[6];
  const float* LR   = (const float*)d_in[7];
  const float* LI   = (const float*)d_in[8];
  const float* CR   = (const float*)d_in[9];
  const float* CI   = (const float*)d_in[10];
  const float* Dv   = (const float*)d_in[11];
  const float* Wgate= (const float*)d_in[12];
  const float* Wout = (const float*)d_in[13];
  const float* bout = (const float*)d_in[14];
  float* out = (float*)d_out;

  const int Bn = 2, L = 4096, DIM = 1024, HID = 4096, H = 512;
  const int M = Bn * L;  // 8192

  char* p = (char*)d_ws;
  auto alloc = [&](size_t bytes) { char* q = p; p += (bytes + 255) & ~(size_t)255; return q; };
  u16* Wxg_t   = (u16*)alloc((size_t)HID * DIM * 2);
  u16* Wdin_t  = (u16*)alloc((size_t)H * DIM * 2);
  u16* Wgate_t = (u16*)alloc((size_t)HID * H * 2);
  u16* Wout_t  = (u16*)alloc((size_t)DIM * HID * 2);
  u16* xbf     = (u16*)alloc((size_t)M * DIM * 2);
  u16* xg      = (u16*)alloc((size_t)M * HID * 2);    // later aliased as e
  float* xdT   = (float*)alloc((size_t)H * M * 4);    // [512][8192]
  float* meanv = (float*)alloc((size_t)M * 4);
  float* invv  = (float*)alloc((size_t)M * 4);
  u16* SRSI    = (u16*)alloc((size_t)L * 1024 * 2);
  u16* Ct      = (u16*)alloc((size_t)H * 1024 * 2);
  float* KT    = (float*)alloc((size_t)H * L * 4);    // [512][4096]
  u16* dTm     = (u16*)alloc((size_t)H * M * 2);      // d^T [512][8192]
  u16* dbuf    = (u16*)alloc((size_t)M * H * 2);      // d   [8192][512]

  // 1) weight transpose+convert
  trans_conv<<<dim3((DIM / 32) * (HID / 32)), 256, 0, stream>>>(Wxg, Wxg_t, DIM, HID);
  trans_conv<<<dim3((DIM / 32) * (H / 32)), 256, 0, stream>>>(Wdin, Wdin_t, DIM, H);
  trans_conv<<<dim3((H / 32) * (HID / 32)), 256, 0, stream>>>(Wgate, Wgate_t, H, HID);
  trans_conv<<<dim3((HID / 32) * (DIM / 32)), 256, 0, stream>>>(Wout, Wout_t, HID, DIM);
  // 2) LN1
  ln_kernel<true><<<dim3(M), 256, 0, stream>>>(idx, n1w, n1b, xbf, DIM);
  // 3) xg = x @ Wxg (bf16)
  gemm_bf16<1><<<dim3((M / 128) * (HID / 128)), 256, 0, stream>>>(
      xbf, Wxg_t, M, HID, DIM, nullptr, xg, nullptr, nullptr, nullptr);
  // 4) xd^T = Wdin_t @ xbf^T  [512][8192] f32
  gemm_bf16<0><<<dim3((H / 128) * (M / 128)), 256, 0, stream>>>(
      Wdin_t, xbf, H, M, DIM, xdT, nullptr, nullptr, nullptr, nullptr);
  // 5) LN2 column stats
  ln_stats<<<dim3(M / 64), 256, 0, stream>>>(xdT, meanv, invv);
  // 6) S and C generation
  kgen_s<<<dim3(L * 1024 / 256), 256, 0, stream>>>(LR, LI, SRSI);
  kgen_c<<<dim3(H * 512 / 256), 256, 0, stream>>>(LR, LI, CR, CI, Ct);
  // 7) K^T = Ct @ SRSI^T  [512][4096] f32
  gemm_bf16<0><<<dim3((H / 128) * (L / 128)), 256, 0, stream>>>(
      Ct, SRSI, H, L, 1024, KT, nullptr, nullptr, nullptr, nullptr);
  // 8) FFT causal conv (+LN2 on the fly, +D*xn) -> d^T bf16
  fft_conv2<<<dim3(Bn * H), 512, 0, stream>>>(xdT, KT, meanv, invv, n2w, n2b, Dv, dTm);
  // 8b) d^T -> d
  trans_bf<<<dim3((H / 32) * (M / 32)), 256, 0, stream>>>(dTm, dbuf, H, M);
  // 9) e = (d @ Wgate) * xg  (bf16, aliases xg)
  gemm_bf16<2><<<dim3((M / 128) * (HID / 128)), 256, 0, stream>>>(
      dbuf, Wgate_t, M, HID, H, nullptr, xg, xg, nullptr, nullptr);
  // 10) out = e @ Wout + bout + idx
  gemm_bf16<3><<<dim3((M / 128) * (DIM / 128)), 256, 0, stream>>>(
      xg, Wout_t, M, DIM, HID, out, nullptr, nullptr, bout, idx);
}

// Round 3
// 463.835 us; speedup vs baseline: 1.4021x; 1.0189x over previous
//
#include <hip/hip_runtime.h>
#include <math.h>

// GSS block on MI355X. Shapes: B=2, L=4096, DIM=1024, HID=4096, H=DSSH=512, N=DSSN=512.
// R3: big GEMMs ported to 256x256 8-wave deep-pipeline template (counted vmcnt,
// raw barriers, XOR slot swizzle with pre-swizzled global source, setprio).

typedef unsigned short u16;
typedef unsigned int u32;
typedef __attribute__((ext_vector_type(8))) __bf16 bf16x8;
typedef __attribute__((ext_vector_type(4))) float f32x4;

__device__ __forceinline__ u16 f2bf(float f) {
  u32 u = __float_as_uint(f);
  u32 r = u + 0x7FFFu + ((u >> 16) & 1u);
  return (u16)(r >> 16);
}
__device__ __forceinline__ float bf2f(u16 h) { return __uint_as_float(((u32)h) << 16); }

// ---------------------------------------------------------------- transpose+convert
__global__ __launch_bounds__(256) void trans_conv(
    const float* __restrict__ in, u16* __restrict__ out, int K, int N) {
  __shared__ float t[32][33];
  int tx = threadIdx.x & 31, ty = threadIdx.x >> 5;
  int nb = N >> 5;
  int k0 = (blockIdx.x / nb) << 5;
  int n0 = (blockIdx.x % nb) << 5;
#pragma unroll
  for (int i = 0; i < 32; i += 8)
    t[ty + i][tx] = in[(size_t)(k0 + ty + i) * N + n0 + tx];
  __syncthreads();
#pragma unroll
  for (int i = 0; i < 32; i += 8)
    out[(size_t)(n0 + ty + i) * K + k0 + tx] = f2bf(t[tx][ty + i]);
}

// bf16 [R][C] -> bf16 [C][R]
__global__ __launch_bounds__(256) void trans_bf(
    const u16* __restrict__ in, u16* __restrict__ out, int R, int C) {
  __shared__ u16 t[32][34];
  int tx = threadIdx.x & 31, ty = threadIdx.x >> 5;
  int nb = C >> 5;
  int r0 = (blockIdx.x / nb) << 5;
  int c0 = (blockIdx.x % nb) << 5;
#pragma unroll
  for (int i = 0; i < 32; i += 8)
    t[ty + i][tx] = in[(size_t)(r0 + ty + i) * C + c0 + tx];
  __syncthreads();
#pragma unroll
  for (int i = 0; i < 32; i += 8)
    out[(size_t)(c0 + ty + i) * R + r0 + tx] = t[tx][ty + i];
}

// ---------------------------------------------------------------- LayerNorm (LN1)
template <bool BOUT>
__global__ void ln_kernel(const float* __restrict__ in, const float* __restrict__ gw,
                          const float* __restrict__ gb, void* outp, int D) {
  int row = blockIdx.x;
  int tid = threadIdx.x;
  const float4* r4 = (const float4*)(in + (size_t)row * D);
  float4 v = r4[tid];
  float s = v.x + v.y + v.z + v.w;
  float ss = fmaf(v.x, v.x, fmaf(v.y, v.y, fmaf(v.z, v.z, v.w * v.w)));
#pragma unroll
  for (int o = 32; o >= 1; o >>= 1) { s += __shfl_xor(s, o); ss += __shfl_xor(ss, o); }
  __shared__ float sa[8], sb[8];
  int nw = blockDim.x >> 6;
  if ((tid & 63) == 0) { sa[tid >> 6] = s; sb[tid >> 6] = ss; }
  __syncthreads();
  float S = 0.f, SS = 0.f;
  for (int i = 0; i < nw; ++i) { S += sa[i]; SS += sb[i]; }
  float mean = S / (float)D;
  float var = SS / (float)D - mean * mean;
  float inv = rsqrtf(var + 1e-5f);
  float4 wv = ((const float4*)gw)[tid];
  float4 bv = ((const float4*)gb)[tid];
  float o0 = (v.x - mean) * inv * wv.x + bv.x;
  float o1 = (v.y - mean) * inv * wv.y + bv.y;
  float o2 = (v.z - mean) * inv * wv.z + bv.z;
  float o3 = (v.w - mean) * inv * wv.w + bv.w;
  if (BOUT) {
    ushort4 o; o.x = f2bf(o0); o.y = f2bf(o1); o.z = f2bf(o2); o.w = f2bf(o3);
    ((ushort4*)outp)[(size_t)row * (D >> 2) + tid] = o;
  } else {
    float4 o; o.x = o0; o.y = o1; o.z = o2; o.w = o3;
    ((float4*)outp)[(size_t)row * (D >> 2) + tid] = o;
  }
}

// ---------------------------------------------------------------- LN2 column stats
__global__ __launch_bounds__(256) void ln_stats(
    const float* __restrict__ xdT, float* __restrict__ meanv, float* __restrict__ invv) {
  int lane = threadIdx.x & 63;
  int seg = threadIdx.x >> 6;
  int col = blockIdx.x * 64 + lane;
  float s = 0.f, ss = 0.f;
  const float* p = xdT + (size_t)(seg * 128) * 8192 + col;
  for (int r = 0; r < 128; ++r) {
    float v = p[(size_t)r * 8192];
    s += v; ss = fmaf(v, v, ss);
  }
  __shared__ float sa[4][64], sb[4][64];
  sa[seg][lane] = s; sb[seg][lane] = ss;
  __syncthreads();
  if (threadIdx.x < 64) {
    float S = sa[0][lane] + sa[1][lane] + sa[2][lane] + sa[3][lane];
    float SS = sb[0][lane] + sb[1][lane] + sb[2][lane] + sb[3][lane];
    float mean = S * (1.0f / 512.0f);
    float var = SS * (1.0f / 512.0f) - mean * mean;
    meanv[blockIdx.x * 64 + lane] = mean;
    invv[blockIdx.x * 64 + lane] = rsqrtf(var + 1e-5f);
  }
}

// ---------------------------------------------------------------- 128x128 GEMM (small shapes)
// C[M,N] = A[M,K] @ Bt[N,K]^T. MODE 0: f32 out.
template <int MODE>
__global__ __launch_bounds__(256) void gemm_bf16(
    const u16* __restrict__ A, const u16* __restrict__ Bt,
    int M, int N, int K,
    float* Cf, u16* Cb, const u16* aux,
    const float* __restrict__ bias, const float* __restrict__ res) {
  __shared__ __align__(16) u16 As[128 * 32];
  __shared__ __align__(16) u16 Bs[128 * 32];
  const int tid = threadIdx.x;
  const int lane = tid & 63;
  const int wid = tid >> 6;
  const int nwg = (int)gridDim.x;
  const int cpx = nwg >> 3;
  const int bid = ((int)blockIdx.x & 7) * cpx + ((int)blockIdx.x >> 3);
  const int tiles_n = N >> 7;
  const int tm = (bid / tiles_n) << 7;
  const int tn = (bid % tiles_n) << 7;

  const int srow = wid * 32 + (lane >> 2);
  const int scol = (lane & 3) << 3;
  const u16* gA = A + (size_t)(tm + srow) * K + scol;
  const u16* gB = Bt + (size_t)(tn + srow) * K + scol;
  const u16* gA2 = gA + (size_t)16 * K;
  const u16* gB2 = gB + (size_t)16 * K;
  auto As3 = (__attribute__((address_space(3))) char*)As;
  auto Bs3 = (__attribute__((address_space(3))) char*)Bs;
  const u32 lds0 = (u32)wid * 2048u;
  const u32 lds1 = lds0 + 1024u;

  const int lr = lane & 15;
  const int kq = lane >> 4;
  const int wr = (wid >> 1) * 64;
  const int wc = (wid & 1) * 64;

  f32x4 acc[4][4] = {};

  for (int k0 = 0; k0 < K; k0 += 32) {
    __builtin_amdgcn_global_load_lds((const __attribute__((address_space(1))) void*)(gA + k0),
                                     (__attribute__((address_space(3))) void*)(As3 + lds0), 16, 0, 0);
    __builtin_amdgcn_global_load_lds((const __attribute__((address_space(1))) void*)(gA2 + k0),
                                     (__attribute__((address_space(3))) void*)(As3 + lds1), 16, 0, 0);
    __builtin_amdgcn_global_load_lds((const __attribute__((address_space(1))) void*)(gB + k0),
                                     (__attribute__((address_space(3))) void*)(Bs3 + lds0), 16, 0, 0);
    __builtin_amdgcn_global_load_lds((const __attribute__((address_space(1))) void*)(gB2 + k0),
                                     (__attribute__((address_space(3))) void*)(Bs3 + lds1), 16, 0, 0);
    __syncthreads();
    bf16x8 af[4], bfr[4];
#pragma unroll
    for (int mi = 0; mi < 4; ++mi)
      af[mi] = *(const bf16x8*)(As + (wr + mi * 16 + lr) * 32 + kq * 8);
#pragma unroll
    for (int ni = 0; ni < 4; ++ni)
      bfr[ni] = *(const bf16x8*)(Bs + (wc + ni * 16 + lr) * 32 + kq * 8);
#pragma unroll
    for (int mi = 0; mi < 4; ++mi)
#pragma unroll
      for (int ni = 0; ni < 4; ++ni)
        acc[mi][ni] = __builtin_amdgcn_mfma_f32_16x16x32_bf16(af[mi], bfr[ni], acc[mi][ni], 0, 0, 0);
    __syncthreads();
  }

  const int orow = tm + wr + kq * 4;
  const int ocol = tn + wc + lr;
#pragma unroll
  for (int mi = 0; mi < 4; ++mi)
#pragma unroll
    for (int ni = 0; ni < 4; ++ni)
#pragma unroll
      for (int j = 0; j < 4; ++j) {
        int r = orow + mi * 16 + j;
        int c = ocol + ni * 16;
        size_t off = (size_t)r * N + c;
        float v = acc[mi][ni][j];
        if (MODE == 0) Cf[off] = v;
        else if (MODE == 1) Cb[off] = f2bf(v);
        else if (MODE == 2) Cb[off] = f2bf(v * bf2f(aux[off]));
        else Cf[off] = v + bias[c] + res[off];
      }
}

// ---------------------------------------------------------------- 256x256 8-wave GEMM
// Deep pipeline: BK=64, double-buffered 128 KiB LDS, counted vmcnt(8), raw
// barriers (no __syncthreads -> no vmcnt(0) drain), XOR slot-swizzle on LDS
// reads with pre-swizzled global source (gload_lds writes linearly).
// MODE 1: bf16 out   2: bf16(C*aux)   3: f32 C+bias[n]+res[m,n]
template <int MODE>
__global__ __launch_bounds__(512, 2) void gemm256(
    const u16* __restrict__ A, const u16* __restrict__ Bt,
    int M, int N, int K,
    float* Cf, u16* Cb, const u16* aux,
    const float* __restrict__ bias, const float* __restrict__ res) {
  __shared__ __align__(16) u16 lds[65536];  // 128 KiB: 2 bufs x (A 32K + B 32K)
  const int tid = threadIdx.x;
  const int lane = tid & 63;
  const int w = tid >> 6;          // wave 0..7
  const int nwg = (int)gridDim.x;
  const int cpx = nwg >> 3;
  const int bid = ((int)blockIdx.x & 7) * cpx + ((int)blockIdx.x >> 3);
  const int tiles_n = N >> 8;
  const int tm = (bid / tiles_n) << 8;
  const int tn = (bid % tiles_n) << 8;

  const int wm = w >> 2;           // row half (0/1) -> 128 rows
  const int wn = w & 3;            // col quarter (0..3) -> 64 cols
  const int lr = lane & 15;
  const int kq = lane >> 4;        // 0..3
  const int l7 = lr & 7;

  // staging constants: lane covers row (.. + w*8 + rsub), logical slot sslot.
  // LDS layout: logical elem (row, slot s) stored at phys slot s^(row&7);
  // gload_lds writes linearly, so the SOURCE is pre-swizzled: sslot = (lane&7)^rsub.
  const int rsub = lane >> 3;              // 0..7
  const int sslot = (lane & 7) ^ rsub;
  const u16* gA = A + (size_t)(tm + w * 8 + rsub) * K + sslot * 8;
  const u16* gB = Bt + (size_t)(tn + w * 8 + rsub) * K + sslot * 8;
  auto ldsc = (__attribute__((address_space(3))) char*)lds;

  f32x4 acc[8][4] = {};
  const int NT = K >> 6;

#define STAGE256(kt, c)                                                                  \
  {                                                                                      \
    const size_t kof = (size_t)((kt) << 6);                                              \
    _Pragma("unroll") for (int h = 0; h < 2; ++h) _Pragma("unroll") for (int i = 0; i < 2; ++i) { \
      u32 dst = ((u32)(c) << 16) + (u32)(h * 16384 + i * 8192 + w * 1024);               \
      __builtin_amdgcn_global_load_lds(                                                  \
          (const __attribute__((address_space(1))) void*)(gA + (size_t)(h * 128 + i * 64) * K + kof), \
          (__attribute__((address_space(3))) void*)(ldsc + dst), 16, 0, 0);              \
      __builtin_amdgcn_global_load_lds(                                                  \
          (const __attribute__((address_space(1))) void*)(gB + (size_t)(h * 128 + i * 64) * K + kof), \
          (__attribute__((address_space(3))) void*)(ldsc + dst + 32768), 16, 0, 0);      \
    }                                                                                    \
  }

  STAGE256(0, 0);
  STAGE256(1, 1);
  asm volatile("s_waitcnt vmcnt(8)" ::: "memory");
  __builtin_amdgcn_s_barrier();

  for (int kt = 0; kt < NT; ++kt) {
    const int c = kt & 1;
    const u32 ab = (u32)c * 32768u;  // u16 index of buffer base
#pragma unroll
    for (int ks = 0; ks < 2; ++ks) {
      const int sl = ((ks << 2) | kq) ^ l7;  // phys slot for this lane (A and B alike)
      bf16x8 af[8], bv[4];
#pragma unroll
      for (int mi = 0; mi < 8; ++mi) {
        int ra = wm * 128 + mi * 16 + lr;
        af[mi] = *(const bf16x8*)&lds[ab + ra * 64 + (sl << 3)];
      }
#pragma unroll
      for (int ni = 0; ni < 4; ++ni) {
        int rb = wn * 64 + ni * 16 + lr;
        bv[ni] = *(const bf16x8*)&lds[ab + 16384 + rb * 64 + (sl << 3)];
      }
      __builtin_amdgcn_s_setprio(1);
#pragma unroll
      for (int mi = 0; mi < 8; ++mi)
#pragma unroll
        for (int ni = 0; ni < 4; ++ni)
          acc[mi][ni] = __builtin_amdgcn_mfma_f32_16x16x32_bf16(af[mi], bv[ni], acc[mi][ni], 0, 0, 0);
      __builtin_amdgcn_s_setprio(0);
    }
    asm volatile("s_waitcnt lgkmcnt(0)" ::: "memory");
    __builtin_amdgcn_s_barrier();          // all waves done reading buf c
    if (kt + 2 < NT) {
      STAGE256(kt + 2, c);                 // overwrite buf c (free now)
      asm volatile("s_waitcnt vmcnt(8)" ::: "memory");  // tile kt+1 loads landed
    } else {
      asm volatile("s_waitcnt vmcnt(0)" ::: "memory");
    }
    __builtin_amdgcn_s_barrier();          // tile kt+1 visible to all waves
  }
#undef STAGE256

  const int orow0 = tm + wm * 128 + kq * 4;
  const int ocol0 = tn + wn * 64 + lr;
#pragma unroll
  for (int mi = 0; mi < 8; ++mi)
#pragma unroll
    for (int ni = 0; ni < 4; ++ni)
#pragma unroll
      for (int j = 0; j < 4; ++j) {
        int r = orow0 + mi * 16 + j;
        int cc = ocol0 + ni * 16;
        size_t off = (size_t)r * N + cc;
        float v = acc[mi][ni][j];
        if (MODE == 1) Cb[off] = f2bf(v);
        else if (MODE == 2) Cb[off] = f2bf(v * bf2f(aux[off]));
        else Cf[off] = v + bias[cc] + res[off];
      }
}

// ---------------------------------------------------------------- DSS kernel generation
__global__ __launch_bounds__(256) void kgen_s(
    const float* __restrict__ LR, const float* __restrict__ LI, u16* __restrict__ SRSI) {
  int idx0 = blockIdx.x * 256 + threadIdx.x;
  int l = idx0 >> 10;
  int kk = idx0 & 1023;
  int n = kk & 511;
  double a = exp((double)LR[n]);
  double om = exp((double)LI[n]);
  double ld = (double)l;
  float decay = (float)exp(-a * ld);
  double th = fmod(om * ld, 6.283185307179586477);
  float c, s;
  sincosf((float)th, &s, &c);
  SRSI[idx0] = f2bf(decay * ((kk < 512) ? c : s));
}

__global__ __launch_bounds__(256) void kgen_c(
    const float* __restrict__ LR, const float* __restrict__ LI,
    const float* __restrict__ CR, const float* __restrict__ CI, u16* __restrict__ Ct) {
  int idx0 = blockIdx.x * 256 + threadIdx.x;  // over 512*512
  int h = idx0 >> 9, n = idx0 & 511;
  float eLR = expf(LR[n]), eLI = expf(LI[n]);
  float lre = -eLR, lim = eLI;
  float er = expf(lre);
  float c, s;
  sincosf(lim, &s, &c);
  float wr = er * c - 1.0f, wi = er * s;
  float den = lre * lre + lim * lim;
  float gr = (wr * lre + wi * lim) / den;
  float gi = (wi * lre - wr * lim) / den;
  float cr = CR[(size_t)h * 512 + n], ci = CI[(size_t)h * 512 + n];
  float ccr = cr * gr - ci * gi;
  float cci = cr * gi + ci * gr;
  Ct[(size_t)h * 1024 + n] = f2bf(ccr);
  Ct[(size_t)h * 1024 + 512 + n] = f2bf(-cci);
}

// ---------------------------------------------------------------- FFT convolution
struct C2 { float x, y; };
__device__ __forceinline__ C2 cadd(C2 a, C2 b) { return {a.x + b.x, a.y + b.y}; }
__device__ __forceinline__ C2 csub(C2 a, C2 b) { return {a.x - b.x, a.y - b.y}; }
__device__ __forceinline__ C2 cmul(C2 a, C2 b) {
  return {a.x * b.x - a.y * b.y, a.x * b.y + a.y * b.x};
}
__device__ __forceinline__ C2 cmulni(C2 a) { return {a.y, -a.x}; }  // * (-i)

__device__ __forceinline__ int swz(int a) {
  return a ^ ((a >> 7) & 15) ^ ((a >> 11) & 3) ^ ((a >> 2) & 8) ^ ((a >> 3) & 2) ^ ((a >> 4) & 4);
}

#define BR13(x) ((int)(__brev((u32)(x)) >> 19))

template <int LOGM>
__device__ __forceinline__ void dif_pass(C2* z, int tid) {
  const int M4 = 1 << LOGM;
  const float inv4m = 1.0f / (float)(4 * M4);
#pragma unroll
  for (int j = 0; j < 4; ++j) {
    int b = tid + j * 512;
    int pos = b & (M4 - 1);
    int i0 = ((b >> LOGM) << (LOGM + 2)) | pos;
    int ia = swz(i0), ib = swz(i0 + M4), ic = swz(i0 + 2 * M4), id = swz(i0 + 3 * M4);
    C2 a = z[ia], bb = z[ib], c = z[ic], d = z[id];
    float rev = -(float)pos * inv4m;
    float wc = __builtin_amdgcn_cosf(rev);
    float ws = __builtin_amdgcn_sinf(rev);
    C2 w = {wc, ws};
    C2 wm = {ws, -wc};
    C2 w2 = {wc * wc - ws * ws, 2.f * wc * ws};
    C2 a1 = cadd(a, c);
    C2 c1 = cmul(csub(a, c), w);
    C2 b1 = cadd(bb, d);
    C2 d1 = cmul(csub(bb, d), wm);
    z[ia] = cadd(a1, b1);
    z[ib] = cmul(csub(a1, b1), w2);
    z[ic] = cadd(c1, d1);
    z[id] = cmul(csub(c1, d1), w2);
  }
}

template <int LOGM>
__device__ __forceinline__ void dit_pass(C2* z, int tid) {
  const int M4 = 1 << LOGM;
  const float inv4m = 1.0f / (float)(4 * M4);
#pragma unroll
  for (int j = 0; j < 4; ++j) {
    int b = tid + j * 512;
    int pos = b & (M4 - 1);
    int i0 = ((b >> LOGM) << (LOGM + 2)) | pos;
    int ia = swz(i0), ib = swz(i0 + M4), ic = swz(i0 + 2 * M4), id = swz(i0 + 3 * M4);
    C2 a = z[ia], bb = z[ib], c = z[ic], d = z[id];
    float rev = -(float)pos * inv4m;
    float wc = __builtin_amdgcn_cosf(rev);
    float ws = __builtin_amdgcn_sinf(rev);
    C2 w = {wc, ws};
    C2 wm = {ws, -wc};
    C2 wa = {wc * wc - ws * ws, 2.f * wc * ws};
    C2 t = cmul(wa, bb);
    C2 a1 = cadd(a, t), b1 = csub(a, t);
    C2 u = cmul(wa, d);
    C2 c1 = cadd(c, u), d1 = csub(c, u);
    C2 v = cmul(w, c1);
    C2 xx = cmul(wm, d1);
    z[ia] = cadd(a1, v);
    z[ic] = csub(a1, v);
    z[ib] = cadd(b1, xx);
    z[id] = csub(b1, xx);
  }
}

#define RS 0.70710678118654752f

__device__ __forceinline__ void dif_r8(C2* z, int tid) {
#pragma unroll
  for (int j = 0; j < 2; ++j) {
    int base = (tid + j * 512) << 3;
    int ad[8]; C2 x[8];
#pragma unroll
    for (int e = 0; e < 8; ++e) { ad[e] = swz(base + e); x[e] = z[ad[e]]; }
    C2 t;
    t = csub(x[0], x[4]); x[0] = cadd(x[0], x[4]); x[4] = t;
    t = csub(x[1], x[5]); x[1] = cadd(x[1], x[5]); x[5] = cmul(t, {RS, -RS});
    t = csub(x[2], x[6]); x[2] = cadd(x[2], x[6]); x[6] = cmulni(t);
    t = csub(x[3], x[7]); x[3] = cadd(x[3], x[7]); x[7] = cmul(t, {-RS, -RS});
    t = csub(x[0], x[2]); x[0] = cadd(x[0], x[2]); x[2] = t;
    t = csub(x[1], x[3]); x[1] = cadd(x[1], x[3]); x[3] = cmulni(t);
    t = csub(x[4], x[6]); x[4] = cadd(x[4], x[6]); x[6] = t;
    t = csub(x[5], x[7]); x[5] = cadd(x[5], x[7]); x[7] = cmulni(t);
    t = csub(x[0], x[1]); x[0] = cadd(x[0], x[1]); x[1] = t;
    t = csub(x[2], x[3]); x[2] = cadd(x[2], x[3]); x[3] = t;
    t = csub(x[4], x[5]); x[4] = cadd(x[4], x[5]); x[5] = t;
    t = csub(x[6], x[7]); x[6] = cadd(x[6], x[7]); x[7] = t;
#pragma unroll
    for (int e = 0; e < 8; ++e) z[ad[e]] = x[e];
  }
}

__device__ __forceinline__ void dit_r8(C2* z, int tid) {
#pragma unroll
  for (int j = 0; j < 2; ++j) {
    int base = (tid + j * 512) << 3;
    int ad[8]; C2 x[8];
#pragma unroll
    for (int e = 0; e < 8; ++e) { ad[e] = swz(base + e); x[e] = z[ad[e]]; }
    C2 t;
    t = x[1]; x[1] = csub(x[0], t); x[0] = cadd(x[0], t);
    t = x[3]; x[3] = csub(x[2], t); x[2] = cadd(x[2], t);
    t = x[5]; x[5] = csub(x[4], t); x[4] = cadd(x[4], t);
    t = x[7]; x[7] = csub(x[6], t); x[6] = cadd(x[6], t);
    t = x[2];          x[2] = csub(x[0], t); x[0] = cadd(x[0], t);
    t = cmulni(x[3]);  x[3] = csub(x[1], t); x[1] = cadd(x[1], t);
    t = x[6];          x[6] = csub(x[4], t); x[4] = cadd(x[4], t);
    t = cmulni(x[7]);  x[7] = csub(x[5], t); x[5] = cadd(x[5], t);
    t = x[4];                    x[4] = csub(x[0], t); x[0] = cadd(x[0], t);
    t = cmul(x[5], {RS, -RS});   x[5] = csub(x[1], t); x[1] = cadd(x[1], t);
    t = cmulni(x[6]);            x[6] = csub(x[2], t); x[2] = cadd(x[2], t);
    t = cmul(x[7], {-RS, -RS});  x[7] = csub(x[3], t); x[3] = cadd(x[3], t);
#pragma unroll
    for (int e = 0; e < 8; ++e) z[ad[e]] = x[e];
  }
}

__global__ __launch_bounds__(512) void fft_conv2(
    const float* __restrict__ xdT, const float* __restrict__ KT,
    const float* __restrict__ meanv, const float* __restrict__ invv,
    const float* __restrict__ n2w, const float* __restrict__ n2b,
    const float* __restrict__ Dv, u16* __restrict__ dT) {
  __shared__ C2 z[8192];
  const int tid = threadIdx.x;
  const int h = blockIdx.x & 511;
  const int b = blockIdx.x >> 9;
  const float* xrow = xdT + ((size_t)h << 13) + (b << 12);
  const float* krow = KT + ((size_t)h << 12);
  const float* mrow = meanv + (b << 12);
  const float* irow = invv + (b << 12);
  const float w2h = n2w[h], b2h = n2b[h], Dh = Dv[h];
  const int l0 = tid << 3;

  float xv[8], kv[8], mv[8], iv[8], xn8[8];
  *(float4*)&xv[0] = *(const float4*)(xrow + l0);
  *(float4*)&xv[4] = *(const float4*)(xrow + l0 + 4);
  *(float4*)&kv[0] = *(const float4*)(krow + l0);
  *(float4*)&kv[4] = *(const float4*)(krow + l0 + 4);
  *(float4*)&mv[0] = *(const float4*)(mrow + l0);
  *(float4*)&mv[4] = *(const float4*)(mrow + l0 + 4);
  *(float4*)&iv[0] = *(const float4*)(irow + l0);
  *(float4*)&iv[4] = *(const float4*)(irow + l0 + 4);
#pragma unroll
  for (int e = 0; e < 8; ++e) {
    xn8[e] = (xv[e] - mv[e]) * iv[e] * w2h + b2h;
    z[swz(l0 + e)] = {xn8[e], kv[e]};
    z[swz(4096 + l0 + e)] = {0.f, 0.f};
  }
  __syncthreads();

  dif_pass<11>(z, tid); __syncthreads();
  dif_pass<9>(z, tid);  __syncthreads();
  dif_pass<7>(z, tid);  __syncthreads();
  dif_pass<5>(z, tid);  __syncthreads();
  dif_pass<3>(z, tid);  __syncthreads();
  dif_r8(z, tid);       __syncthreads();

  C2 P[16];
#pragma unroll
  for (int it = 0; it < 16; ++it) {
    int p = tid + it * 512;
    int k = BR13(p);
    int km = (8192 - k) & 8191;
    int p2 = BR13(km);
    C2 Zk = z[swz(p)], Zm = z[swz(p2)];
    float xr = Zk.x + Zm.x, xi2 = Zk.y - Zm.y;
    float kr = Zk.y + Zm.y, ki = Zm.x - Zk.x;
    P[it] = {xr * kr - xi2 * ki, -(xr * ki + xi2 * kr)};
  }
  __syncthreads();
#pragma unroll
  for (int it = 0; it < 16; ++it) z[swz(tid + it * 512)] = P[it];
  __syncthreads();

  dit_r8(z, tid);       __syncthreads();
  dit_pass<3>(z, tid);  __syncthreads();
  dit_pass<5>(z, tid);  __syncthreads();
  dit_pass<7>(z, tid);  __syncthreads();
  dit_pass<9>(z, tid);  __syncthreads();
  dit_pass<11>(z, tid); __syncthreads();

  const float sc = 1.0f / 32768.0f;
  u16 o[8];
#pragma unroll
  for (int e = 0; e < 8; ++e) {
    float y = z[swz(l0 + e)].x * sc;
    o[e] = f2bf(fmaf(Dh, xn8[e], y));
  }
  uint4 pk;
  pk.x = (u32)o[0] | ((u32)o[1] << 16);
  pk.y = (u32)o[2] | ((u32)o[3] << 16);
  pk.z = (u32)o[4] | ((u32)o[5] << 16);
  pk.w = (u32)o[6] | ((u32)o[7] << 16);
  *(uint4*)(dT + ((size_t)h << 13) + (b << 12) + l0) = pk;
}

// ---------------------------------------------------------------- launch
extern "C" void kernel_launch(void* const* d_in, const int* in_sizes, int n_in,
                              void* d_out, int out_size, void* d_ws, size_t ws_size,
                              hipStream_t stream) {
  (void)in_sizes; (void)n_in; (void)out_size; (void)ws_size;
  const float* idx  = (const float*)d_in[0];
  const float* n1w  = (const float*)d_in[1];
  const float* n1b  = (const float*)d_in[2];
  const float* Wxg  = (const float*)d_in[3];
  const float* Wdin = (const float*)d_in[4];
  const float* n2w  = (const float*)d_in[5];
  const float* n2b  = (const float*)d_in[6];
  const float* LR   = (const float*)d_in[7];
  const float* LI   = (const float*)d_in[8];
  const float* CR   = (const float*)d_in[9];
  const float* CI   = (const float*)d_in[10];
  const float* Dv   = (const float*)d_in[11];
  const float* Wgate= (const float*)d_in[12];
  const float* Wout = (const float*)d_in[13];
  const float* bout = (const float*)d_in[14];
  float* out = (float*)d_out;

  const int Bn = 2, L = 4096, DIM = 1024, HID = 4096, H = 512;
  const int M = Bn * L;  // 8192

  char* p = (char*)d_ws;
  auto alloc = [&](size_t bytes) { char* q = p; p += (bytes + 255) & ~(size_t)255; return q; };
  u16* Wxg_t   = (u16*)alloc((size_t)HID * DIM * 2);
  u16* Wdin_t  = (u16*)alloc((size_t)H * DIM * 2);
  u16* Wgate_t = (u16*)alloc((size_t)HID * H * 2);
  u16* Wout_t  = (u16*)alloc((size_t)DIM * HID * 2);
  u16* xbf     = (u16*)alloc((size_t)M * DIM * 2);
  u16* xg      = (u16*)alloc((size_t)M * HID * 2);    // later aliased as e
  float* xdT   = (float*)alloc((size_t)H * M * 4);    // [512][8192]
  float* meanv = (float*)alloc((size_t)M * 4);
  float* invv  = (float*)alloc((size_t)M * 4);
  u16* SRSI    = (u16*)alloc((size_t)L * 1024 * 2);
  u16* Ct      = (u16*)alloc((size_t)H * 1024 * 2);
  float* KT    = (float*)alloc((size_t)H * L * 4);    // [512][4096]
  u16* dTm     = (u16*)alloc((size_t)H * M * 2);      // d^T [512][8192]
  u16* dbuf    = (u16*)alloc((size_t)M * H * 2);      // d   [8192][512]

  // 1) weight transpose+convert
  trans_conv<<<dim3((DIM / 32) * (HID / 32)), 256, 0, stream>>>(Wxg, Wxg_t, DIM, HID);
  trans_conv<<<dim3((DIM / 32) * (H / 32)), 256, 0, stream>>>(Wdin, Wdin_t, DIM, H);
  trans_conv<<<dim3((H / 32) * (HID / 32)), 256, 0, stream>>>(Wgate, Wgate_t, H, HID);
  trans_conv<<<dim3((HID / 32) * (DIM / 32)), 256, 0, stream>>>(Wout, Wout_t, HID, DIM);
  // 2) LN1
  ln_kernel<true><<<dim3(M), 256, 0, stream>>>(idx, n1w, n1b, xbf, DIM);
  // 3) xg = x @ Wxg (bf16) — 256x256 pipeline
  gemm256<1><<<dim3((M / 256) * (HID / 256)), 512, 0, stream>>>(
      xbf, Wxg_t, M, HID, DIM, nullptr, xg, nullptr, nullptr, nullptr);
  // 4) xd^T = Wdin_t @ xbf^T  [512][8192] f32 (small M -> 128x128)
  gemm_bf16<0><<<dim3((H / 128) * (M / 128)), 256, 0, stream>>>(
      Wdin_t, xbf, H, M, DIM, xdT, nullptr, nullptr, nullptr, nullptr);
  // 5) LN2 column stats
  ln_stats<<<dim3(M / 64), 256, 0, stream>>>(xdT, meanv, invv);
  // 6) S and C generation
  kgen_s<<<dim3(L * 1024 / 256), 256, 0, stream>>>(LR, LI, SRSI);
  kgen_c<<<dim3(H * 512 / 256), 256, 0, stream>>>(LR, LI, CR, CI, Ct);
  // 7) K^T = Ct @ SRSI^T  [512][4096] f32 (small M -> 128x128)
  gemm_bf16<0><<<dim3((H / 128) * (L / 128)), 256, 0, stream>>>(
      Ct, SRSI, H, L, 1024, KT, nullptr, nullptr, nullptr, nullptr);
  // 8) FFT causal conv (+LN2 on the fly, +D*xn) -> d^T bf16
  fft_conv2<<<dim3(Bn * H), 512, 0, stream>>>(xdT, KT, meanv, invv, n2w, n2b, Dv, dTm);
  // 8b) d^T -> d
  trans_bf<<<dim3((H / 32) * (M / 32)), 256, 0, stream>>>(dTm, dbuf, H, M);
  // 9) e = (d @ Wgate) * xg  (bf16, aliases xg) — 256x256 pipeline
  gemm256<2><<<dim3((M / 256) * (HID / 256)), 512, 0, stream>>>(
      dbuf, Wgate_t, M, HID, H, nullptr, xg, xg, nullptr, nullptr);
  // 10) out = e @ Wout + bout + idx — 256x256 pipeline
  gemm256<3><<<dim3((M / 256) * (DIM / 256)), 512, 0, stream>>>(
      xg, Wout_t, M, DIM, HID, out, nullptr, nullptr, bout, idx);
}

// Round 4
// 414.438 us; speedup vs baseline: 1.5693x; 1.1192x over previous
//
#include <hip/hip_runtime.h>
#include <math.h>

// GSS block on MI355X. Shapes: B=2, L=4096, DIM=1024, HID=4096, H=DSSH=512, N=DSSN=512.
// R4: gemm256 templated on BN (MODE3 -> 256x128 so grid fills all 256 CUs);
// K-loop switched to the verified 2-phase minimum schedule: STAGE-early,
// one vmcnt(0)+barrier per K-tile (stage latency hides under MFMA phase).

typedef unsigned short u16;
typedef unsigned int u32;
typedef __attribute__((ext_vector_type(8))) __bf16 bf16x8;
typedef __attribute__((ext_vector_type(4))) float f32x4;

__device__ __forceinline__ u16 f2bf(float f) {
  u32 u = __float_as_uint(f);
  u32 r = u + 0x7FFFu + ((u >> 16) & 1u);
  return (u16)(r >> 16);
}
__device__ __forceinline__ float bf2f(u16 h) { return __uint_as_float(((u32)h) << 16); }

// ---------------------------------------------------------------- transpose+convert
__global__ __launch_bounds__(256) void trans_conv(
    const float* __restrict__ in, u16* __restrict__ out, int K, int N) {
  __shared__ float t[32][33];
  int tx = threadIdx.x & 31, ty = threadIdx.x >> 5;
  int nb = N >> 5;
  int k0 = (blockIdx.x / nb) << 5;
  int n0 = (blockIdx.x % nb) << 5;
#pragma unroll
  for (int i = 0; i < 32; i += 8)
    t[ty + i][tx] = in[(size_t)(k0 + ty + i) * N + n0 + tx];
  __syncthreads();
#pragma unroll
  for (int i = 0; i < 32; i += 8)
    out[(size_t)(n0 + ty + i) * K + k0 + tx] = f2bf(t[tx][ty + i]);
}

// bf16 [R][C] -> bf16 [C][R]
__global__ __launch_bounds__(256) void trans_bf(
    const u16* __restrict__ in, u16* __restrict__ out, int R, int C) {
  __shared__ u16 t[32][34];
  int tx = threadIdx.x & 31, ty = threadIdx.x >> 5;
  int nb = C >> 5;
  int r0 = (blockIdx.x / nb) << 5;
  int c0 = (blockIdx.x % nb) << 5;
#pragma unroll
  for (int i = 0; i < 32; i += 8)
    t[ty + i][tx] = in[(size_t)(r0 + ty + i) * C + c0 + tx];
  __syncthreads();
#pragma unroll
  for (int i = 0; i < 32; i += 8)
    out[(size_t)(c0 + ty + i) * R + r0 + tx] = t[tx][ty + i];
}

// ---------------------------------------------------------------- LayerNorm (LN1)
template <bool BOUT>
__global__ void ln_kernel(const float* __restrict__ in, const float* __restrict__ gw,
                          const float* __restrict__ gb, void* outp, int D) {
  int row = blockIdx.x;
  int tid = threadIdx.x;
  const float4* r4 = (const float4*)(in + (size_t)row * D);
  float4 v = r4[tid];
  float s = v.x + v.y + v.z + v.w;
  float ss = fmaf(v.x, v.x, fmaf(v.y, v.y, fmaf(v.z, v.z, v.w * v.w)));
#pragma unroll
  for (int o = 32; o >= 1; o >>= 1) { s += __shfl_xor(s, o); ss += __shfl_xor(ss, o); }
  __shared__ float sa[8], sb[8];
  int nw = blockDim.x >> 6;
  if ((tid & 63) == 0) { sa[tid >> 6] = s; sb[tid >> 6] = ss; }
  __syncthreads();
  float S = 0.f, SS = 0.f;
  for (int i = 0; i < nw; ++i) { S += sa[i]; SS += sb[i]; }
  float mean = S / (float)D;
  float var = SS / (float)D - mean * mean;
  float inv = rsqrtf(var + 1e-5f);
  float4 wv = ((const float4*)gw)[tid];
  float4 bv = ((const float4*)gb)[tid];
  float o0 = (v.x - mean) * inv * wv.x + bv.x;
  float o1 = (v.y - mean) * inv * wv.y + bv.y;
  float o2 = (v.z - mean) * inv * wv.z + bv.z;
  float o3 = (v.w - mean) * inv * wv.w + bv.w;
  if (BOUT) {
    ushort4 o; o.x = f2bf(o0); o.y = f2bf(o1); o.z = f2bf(o2); o.w = f2bf(o3);
    ((ushort4*)outp)[(size_t)row * (D >> 2) + tid] = o;
  } else {
    float4 o; o.x = o0; o.y = o1; o.z = o2; o.w = o3;
    ((float4*)outp)[(size_t)row * (D >> 2) + tid] = o;
  }
}

// ---------------------------------------------------------------- LN2 column stats
__global__ __launch_bounds__(256) void ln_stats(
    const float* __restrict__ xdT, float* __restrict__ meanv, float* __restrict__ invv) {
  int lane = threadIdx.x & 63;
  int seg = threadIdx.x >> 6;
  int col = blockIdx.x * 64 + lane;
  float s = 0.f, ss = 0.f;
  const float* p = xdT + (size_t)(seg * 128) * 8192 + col;
  for (int r = 0; r < 128; ++r) {
    float v = p[(size_t)r * 8192];
    s += v; ss = fmaf(v, v, ss);
  }
  __shared__ float sa[4][64], sb[4][64];
  sa[seg][lane] = s; sb[seg][lane] = ss;
  __syncthreads();
  if (threadIdx.x < 64) {
    float S = sa[0][lane] + sa[1][lane] + sa[2][lane] + sa[3][lane];
    float SS = sb[0][lane] + sb[1][lane] + sb[2][lane] + sb[3][lane];
    float mean = S * (1.0f / 512.0f);
    float var = SS * (1.0f / 512.0f) - mean * mean;
    meanv[blockIdx.x * 64 + lane] = mean;
    invv[blockIdx.x * 64 + lane] = rsqrtf(var + 1e-5f);
  }
}

// ---------------------------------------------------------------- 128x128 GEMM (small shapes)
template <int MODE>
__global__ __launch_bounds__(256) void gemm_bf16(
    const u16* __restrict__ A, const u16* __restrict__ Bt,
    int M, int N, int K,
    float* Cf, u16* Cb, const u16* aux,
    const float* __restrict__ bias, const float* __restrict__ res) {
  __shared__ __align__(16) u16 As[128 * 32];
  __shared__ __align__(16) u16 Bs[128 * 32];
  const int tid = threadIdx.x;
  const int lane = tid & 63;
  const int wid = tid >> 6;
  const int nwg = (int)gridDim.x;
  const int cpx = nwg >> 3;
  const int bid = ((int)blockIdx.x & 7) * cpx + ((int)blockIdx.x >> 3);
  const int tiles_n = N >> 7;
  const int tm = (bid / tiles_n) << 7;
  const int tn = (bid % tiles_n) << 7;

  const int srow = wid * 32 + (lane >> 2);
  const int scol = (lane & 3) << 3;
  const u16* gA = A + (size_t)(tm + srow) * K + scol;
  const u16* gB = Bt + (size_t)(tn + srow) * K + scol;
  const u16* gA2 = gA + (size_t)16 * K;
  const u16* gB2 = gB + (size_t)16 * K;
  auto As3 = (__attribute__((address_space(3))) char*)As;
  auto Bs3 = (__attribute__((address_space(3))) char*)Bs;
  const u32 lds0 = (u32)wid * 2048u;
  const u32 lds1 = lds0 + 1024u;

  const int lr = lane & 15;
  const int kq = lane >> 4;
  const int wr = (wid >> 1) * 64;
  const int wc = (wid & 1) * 64;

  f32x4 acc[4][4] = {};

  for (int k0 = 0; k0 < K; k0 += 32) {
    __builtin_amdgcn_global_load_lds((const __attribute__((address_space(1))) void*)(gA + k0),
                                     (__attribute__((address_space(3))) void*)(As3 + lds0), 16, 0, 0);
    __builtin_amdgcn_global_load_lds((const __attribute__((address_space(1))) void*)(gA2 + k0),
                                     (__attribute__((address_space(3))) void*)(As3 + lds1), 16, 0, 0);
    __builtin_amdgcn_global_load_lds((const __attribute__((address_space(1))) void*)(gB + k0),
                                     (__attribute__((address_space(3))) void*)(Bs3 + lds0), 16, 0, 0);
    __builtin_amdgcn_global_load_lds((const __attribute__((address_space(1))) void*)(gB2 + k0),
                                     (__attribute__((address_space(3))) void*)(Bs3 + lds1), 16, 0, 0);
    __syncthreads();
    bf16x8 af[4], bfr[4];
#pragma unroll
    for (int mi = 0; mi < 4; ++mi)
      af[mi] = *(const bf16x8*)(As + (wr + mi * 16 + lr) * 32 + kq * 8);
#pragma unroll
    for (int ni = 0; ni < 4; ++ni)
      bfr[ni] = *(const bf16x8*)(Bs + (wc + ni * 16 + lr) * 32 + kq * 8);
#pragma unroll
    for (int mi = 0; mi < 4; ++mi)
#pragma unroll
      for (int ni = 0; ni < 4; ++ni)
        acc[mi][ni] = __builtin_amdgcn_mfma_f32_16x16x32_bf16(af[mi], bfr[ni], acc[mi][ni], 0, 0, 0);
    __syncthreads();
  }

  const int orow = tm + wr + kq * 4;
  const int ocol = tn + wc + lr;
#pragma unroll
  for (int mi = 0; mi < 4; ++mi)
#pragma unroll
    for (int ni = 0; ni < 4; ++ni)
#pragma unroll
      for (int j = 0; j < 4; ++j) {
        int r = orow + mi * 16 + j;
        int c = ocol + ni * 16;
        size_t off = (size_t)r * N + c;
        float v = acc[mi][ni][j];
        if (MODE == 0) Cf[off] = v;
        else if (MODE == 1) Cb[off] = f2bf(v);
        else if (MODE == 2) Cb[off] = f2bf(v * bf2f(aux[off]));
        else Cf[off] = v + bias[c] + res[off];
      }
}

// ---------------------------------------------------------------- 256xBN 8-wave GEMM
// 2-phase minimum schedule (T3-min): per K-tile {STAGE(kt+1 -> other buf) FIRST;
// ds_read(cur)+MFMA; vmcnt(0); ONE barrier}. XOR slot-swizzle on reads with
// pre-swizzled global source (gload_lds writes linearly).
// MODE 1: bf16 out   2: bf16(C*aux)   3: f32 C+bias[n]+res[m,n]
template <int MODE, int BN>
__global__ __launch_bounds__(512, 2) void gemm256(
    const u16* __restrict__ A, const u16* __restrict__ Bt,
    int M, int N, int K,
    float* Cf, u16* Cb, const u16* aux,
    const float* __restrict__ bias, const float* __restrict__ res) {
  constexpr int BM = 256;
  constexpr int WN = BN / 64;        // waves along N
  constexpr int WM = 8 / WN;         // waves along M
  constexpr int MI = BM / WM / 16;   // fragments along M per wave
  constexpr int NI = 4;              // fragments along N per wave (64 cols)
  constexpr int LA = BM / 64;        // A stage loads per wave
  constexpr int LB = BN / 64;        // B stage loads per wave
  constexpr int ASZ = BM * 64;       // u16 per A buffer
  constexpr int BUF = ASZ + BN * 64; // u16 per (A+B) buffer
  __shared__ __align__(16) u16 lds[2 * BUF];

  const int tid = threadIdx.x;
  const int lane = tid & 63;
  const int w = tid >> 6;
  const int nwg = (int)gridDim.x;
  const int cpx = nwg >> 3;
  const int bid = ((int)blockIdx.x & 7) * cpx + ((int)blockIdx.x >> 3);
  const int tiles_n = N / BN;
  const int tm = (bid / tiles_n) * BM;
  const int tn = (bid % tiles_n) * BN;

  const int wm = w / WN;
  const int wn = w % WN;
  const int lr = lane & 15;
  const int kq = lane >> 4;
  const int l7 = lane & 7;

  // staging: lane covers 8 rows (rsub) x 8 slots; source pre-swizzled so that
  // linear LDS write realizes phys_slot = logical_slot ^ (row&7).
  const int rsub = lane >> 3;
  const int sslot = (lane & 7) ^ rsub;
  const u16* gA = A + (size_t)(tm + w * (BM / 8) + rsub) * K + sslot * 8;
  const u16* gB = Bt + (size_t)(tn + w * (BN / 8) + rsub) * K + sslot * 8;
  auto ldsc = (__attribute__((address_space(3))) char*)lds;

  auto STAGE = [&](int kt, int c) {
    const size_t kof = (size_t)kt << 6;
#pragma unroll
    for (int i = 0; i < LA; ++i) {
      u32 dst = (u32)(c * BUF + (w * (BM / 8) + i * 8) * 64) * 2u;
      __builtin_amdgcn_global_load_lds(
          (const __attribute__((address_space(1))) void*)(gA + (size_t)(i * 8) * K + kof),
          (__attribute__((address_space(3))) void*)(ldsc + dst), 16, 0, 0);
    }
#pragma unroll
    for (int i = 0; i < LB; ++i) {
      u32 dst = (u32)(c * BUF + ASZ + (w * (BN / 8) + i * 8) * 64) * 2u;
      __builtin_amdgcn_global_load_lds(
          (const __attribute__((address_space(1))) void*)(gB + (size_t)(i * 8) * K + kof),
          (__attribute__((address_space(3))) void*)(ldsc + dst), 16, 0, 0);
    }
  };

  f32x4 acc[MI][NI] = {};
  const int NT = K >> 6;

  STAGE(0, 0);
  asm volatile("s_waitcnt vmcnt(0)" ::: "memory");
  __builtin_amdgcn_s_barrier();
  __builtin_amdgcn_sched_barrier(0);

  int cur = 0;
  for (int kt = 0; kt < NT; ++kt) {
    if (kt + 1 < NT) STAGE(kt + 1, cur ^ 1);   // issue-early: hides under MFMA phase
    const u32 ab = (u32)cur * BUF;
#pragma unroll
    for (int ks = 0; ks < 2; ++ks) {
      const int slp = ((((ks << 2) | kq)) ^ l7) << 3;
      bf16x8 af[MI], bv[NI];
#pragma unroll
      for (int mi = 0; mi < MI; ++mi) {
        int ra = wm * (MI * 16) + mi * 16 + lr;
        af[mi] = *(const bf16x8*)&lds[ab + ra * 64 + slp];
      }
#pragma unroll
      for (int ni = 0; ni < NI; ++ni) {
        int rb = wn * 64 + ni * 16 + lr;
        bv[ni] = *(const bf16x8*)&lds[ab + ASZ + rb * 64 + slp];
      }
      __builtin_amdgcn_s_setprio(1);
#pragma unroll
      for (int mi = 0; mi < MI; ++mi)
#pragma unroll
        for (int ni = 0; ni < NI; ++ni)
          acc[mi][ni] = __builtin_amdgcn_mfma_f32_16x16x32_bf16(af[mi], bv[ni], acc[mi][ni], 0, 0, 0);
      __builtin_amdgcn_s_setprio(0);
    }
    // all of this wave's ds_reads are consumed (MFMA issue forces lgkmcnt);
    // wait for next tile's stage loads, then one barrier.
    asm volatile("s_waitcnt vmcnt(0)" ::: "memory");
    __builtin_amdgcn_s_barrier();
    __builtin_amdgcn_sched_barrier(0);
    cur ^= 1;
  }

  const int orow0 = tm + wm * (MI * 16) + kq * 4;
  const int ocol0 = tn + wn * 64 + lr;
#pragma unroll
  for (int mi = 0; mi < MI; ++mi)
#pragma unroll
    for (int ni = 0; ni < NI; ++ni)
#pragma unroll
      for (int j = 0; j < 4; ++j) {
        int r = orow0 + mi * 16 + j;
        int cc = ocol0 + ni * 16;
        size_t off = (size_t)r * N + cc;
        float v = acc[mi][ni][j];
        if (MODE == 1) Cb[off] = f2bf(v);
        else if (MODE == 2) Cb[off] = f2bf(v * bf2f(aux[off]));
        else Cf[off] = v + bias[cc] + res[off];
      }
}

// ---------------------------------------------------------------- DSS kernel generation
__global__ __launch_bounds__(256) void kgen_s(
    const float* __restrict__ LR, const float* __restrict__ LI, u16* __restrict__ SRSI) {
  int idx0 = blockIdx.x * 256 + threadIdx.x;
  int l = idx0 >> 10;
  int kk = idx0 & 1023;
  int n = kk & 511;
  double a = exp((double)LR[n]);
  double om = exp((double)LI[n]);
  double ld = (double)l;
  float decay = (float)exp(-a * ld);
  double th = fmod(om * ld, 6.283185307179586477);
  float c, s;
  sincosf((float)th, &s, &c);
  SRSI[idx0] = f2bf(decay * ((kk < 512) ? c : s));
}

__global__ __launch_bounds__(256) void kgen_c(
    const float* __restrict__ LR, const float* __restrict__ LI,
    const float* __restrict__ CR, const float* __restrict__ CI, u16* __restrict__ Ct) {
  int idx0 = blockIdx.x * 256 + threadIdx.x;  // over 512*512
  int h = idx0 >> 9, n = idx0 & 511;
  float eLR = expf(LR[n]), eLI = expf(LI[n]);
  float lre = -eLR, lim = eLI;
  float er = expf(lre);
  float c, s;
  sincosf(lim, &s, &c);
  float wr = er * c - 1.0f, wi = er * s;
  float den = lre * lre + lim * lim;
  float gr = (wr * lre + wi * lim) / den;
  float gi = (wi * lre - wr * lim) / den;
  float cr = CR[(size_t)h * 512 + n], ci = CI[(size_t)h * 512 + n];
  float ccr = cr * gr - ci * gi;
  float cci = cr * gi + ci * gr;
  Ct[(size_t)h * 1024 + n] = f2bf(ccr);
  Ct[(size_t)h * 1024 + 512 + n] = f2bf(-cci);
}

// ---------------------------------------------------------------- FFT convolution
struct C2 { float x, y; };
__device__ __forceinline__ C2 cadd(C2 a, C2 b) { return {a.x + b.x, a.y + b.y}; }
__device__ __forceinline__ C2 csub(C2 a, C2 b) { return {a.x - b.x, a.y - b.y}; }
__device__ __forceinline__ C2 cmul(C2 a, C2 b) {
  return {a.x * b.x - a.y * b.y, a.x * b.y + a.y * b.x};
}
__device__ __forceinline__ C2 cmulni(C2 a) { return {a.y, -a.x}; }  // * (-i)

__device__ __forceinline__ int swz(int a) {
  return a ^ ((a >> 7) & 15) ^ ((a >> 11) & 3) ^ ((a >> 2) & 8) ^ ((a >> 3) & 2) ^ ((a >> 4) & 4);
}

#define BR13(x) ((int)(__brev((u32)(x)) >> 19))

template <int LOGM>
__device__ __forceinline__ void dif_pass(C2* z, int tid) {
  const int M4 = 1 << LOGM;
  const float inv4m = 1.0f / (float)(4 * M4);
#pragma unroll
  for (int j = 0; j < 4; ++j) {
    int b = tid + j * 512;
    int pos = b & (M4 - 1);
    int i0 = ((b >> LOGM) << (LOGM + 2)) | pos;
    int ia = swz(i0), ib = swz(i0 + M4), ic = swz(i0 + 2 * M4), id = swz(i0 + 3 * M4);
    C2 a = z[ia], bb = z[ib], c = z[ic], d = z[id];
    float rev = -(float)pos * inv4m;
    float wc = __builtin_amdgcn_cosf(rev);
    float ws = __builtin_amdgcn_sinf(rev);
    C2 w = {wc, ws};
    C2 wm = {ws, -wc};
    C2 w2 = {wc * wc - ws * ws, 2.f * wc * ws};
    C2 a1 = cadd(a, c);
    C2 c1 = cmul(csub(a, c), w);
    C2 b1 = cadd(bb, d);
    C2 d1 = cmul(csub(bb, d), wm);
    z[ia] = cadd(a1, b1);
    z[ib] = cmul(csub(a1, b1), w2);
    z[ic] = cadd(c1, d1);
    z[id] = cmul(csub(c1, d1), w2);
  }
}

template <int LOGM>
__device__ __forceinline__ void dit_pass(C2* z, int tid) {
  const int M4 = 1 << LOGM;
  const float inv4m = 1.0f / (float)(4 * M4);
#pragma unroll
  for (int j = 0; j < 4; ++j) {
    int b = tid + j * 512;
    int pos = b & (M4 - 1);
    int i0 = ((b >> LOGM) << (LOGM + 2)) | pos;
    int ia = swz(i0), ib = swz(i0 + M4), ic = swz(i0 + 2 * M4), id = swz(i0 + 3 * M4);
    C2 a = z[ia], bb = z[ib], c = z[ic], d = z[id];
    float rev = -(float)pos * inv4m;
    float wc = __builtin_amdgcn_cosf(rev);
    float ws = __builtin_amdgcn_sinf(rev);
    C2 w = {wc, ws};
    C2 wm = {ws, -wc};
    C2 wa = {wc * wc - ws * ws, 2.f * wc * ws};
    C2 t = cmul(wa, bb);
    C2 a1 = cadd(a, t), b1 = csub(a, t);
    C2 u = cmul(wa, d);
    C2 c1 = cadd(c, u), d1 = csub(c, u);
    C2 v = cmul(w, c1);
    C2 xx = cmul(wm, d1);
    z[ia] = cadd(a1, v);
    z[ic] = csub(a1, v);
    z[ib] = cadd(b1, xx);
    z[id] = csub(b1, xx);
  }
}

#define RS 0.70710678118654752f

__device__ __forceinline__ void dif_r8(C2* z, int tid) {
#pragma unroll
  for (int j = 0; j < 2; ++j) {
    int base = (tid + j * 512) << 3;
    int ad[8]; C2 x[8];
#pragma unroll
    for (int e = 0; e < 8; ++e) { ad[e] = swz(base + e); x[e] = z[ad[e]]; }
    C2 t;
    t = csub(x[0], x[4]); x[0] = cadd(x[0], x[4]); x[4] = t;
    t = csub(x[1], x[5]); x[1] = cadd(x[1], x[5]); x[5] = cmul(t, {RS, -RS});
    t = csub(x[2], x[6]); x[2] = cadd(x[2], x[6]); x[6] = cmulni(t);
    t = csub(x[3], x[7]); x[3] = cadd(x[3], x[7]); x[7] = cmul(t, {-RS, -RS});
    t = csub(x[0], x[2]); x[0] = cadd(x[0], x[2]); x[2] = t;
    t = csub(x[1], x[3]); x[1] = cadd(x[1], x[3]); x[3] = cmulni(t);
    t = csub(x[4], x[6]); x[4] = cadd(x[4], x[6]); x[6] = t;
    t = csub(x[5], x[7]); x[5] = cadd(x[5], x[7]); x[7] = cmulni(t);
    t = csub(x[0], x[1]); x[0] = cadd(x[0], x[1]); x[1] = t;
    t = csub(x[2], x[3]); x[2] = cadd(x[2], x[3]); x[3] = t;
    t = csub(x[4], x[5]); x[4] = cadd(x[4], x[5]); x[5] = t;
    t = csub(x[6], x[7]); x[6] = cadd(x[6], x[7]); x[7] = t;
#pragma unroll
    for (int e = 0; e < 8; ++e) z[ad[e]] = x[e];
  }
}

__device__ __forceinline__ void dit_r8(C2* z, int tid) {
#pragma unroll
  for (int j = 0; j < 2; ++j) {
    int base = (tid + j * 512) << 3;
    int ad[8]; C2 x[8];
#pragma unroll
    for (int e = 0; e < 8; ++e) { ad[e] = swz(base + e); x[e] = z[ad[e]]; }
    C2 t;
    t = x[1]; x[1] = csub(x[0], t); x[0] = cadd(x[0], t);
    t = x[3]; x[3] = csub(x[2], t); x[2] = cadd(x[2], t);
    t = x[5]; x[5] = csub(x[4], t); x[4] = cadd(x[4], t);
    t = x[7]; x[7] = csub(x[6], t); x[6] = cadd(x[6], t);
    t = x[2];          x[2] = csub(x[0], t); x[0] = cadd(x[0], t);
    t = cmulni(x[3]);  x[3] = csub(x[1], t); x[1] = cadd(x[1], t);
    t = x[6];          x[6] = csub(x[4], t); x[4] = cadd(x[4], t);
    t = cmulni(x[7]);  x[7] = csub(x[5], t); x[5] = cadd(x[5], t);
    t = x[4];                    x[4] = csub(x[0], t); x[0] = cadd(x[0], t);
    t = cmul(x[5], {RS, -RS});   x[5] = csub(x[1], t); x[1] = cadd(x[1], t);
    t = cmulni(x[6]);            x[6] = csub(x[2], t); x[2] = cadd(x[2], t);
    t = cmul(x[7], {-RS, -RS});  x[7] = csub(x[3], t); x[3] = cadd(x[3], t);
#pragma unroll
    for (int e = 0; e < 8; ++e) z[ad[e]] = x[e];
  }
}

__global__ __launch_bounds__(512) void fft_conv2(
    const float* __restrict__ xdT, const float* __restrict__ KT,
    const float* __restrict__ meanv, const float* __restrict__ invv,
    const float* __restrict__ n2w, const float* __restrict__ n2b,
    const float* __restrict__ Dv, u16* __restrict__ dT) {
  __shared__ C2 z[8192];
  const int tid = threadIdx.x;
  const int h = blockIdx.x & 511;
  const int b = blockIdx.x >> 9;
  const float* xrow = xdT + ((size_t)h << 13) + (b << 12);
  const float* krow = KT + ((size_t)h << 12);
  const float* mrow = meanv + (b << 12);
  const float* irow = invv + (b << 12);
  const float w2h = n2w[h], b2h = n2b[h], Dh = Dv[h];
  const int l0 = tid << 3;

  float xv[8], kv[8], mv[8], iv[8], xn8[8];
  *(float4*)&xv[0] = *(const float4*)(xrow + l0);
  *(float4*)&xv[4] = *(const float4*)(xrow + l0 + 4);
  *(float4*)&kv[0] = *(const float4*)(krow + l0);
  *(float4*)&kv[4] = *(const float4*)(krow + l0 + 4);
  *(float4*)&mv[0] = *(const float4*)(mrow + l0);
  *(float4*)&mv[4] = *(const float4*)(mrow + l0 + 4);
  *(float4*)&iv[0] = *(const float4*)(irow + l0);
  *(float4*)&iv[4] = *(const float4*)(irow + l0 + 4);
#pragma unroll
  for (int e = 0; e < 8; ++e) {
    xn8[e] = (xv[e] - mv[e]) * iv[e] * w2h + b2h;
    z[swz(l0 + e)] = {xn8[e], kv[e]};
    z[swz(4096 + l0 + e)] = {0.f, 0.f};
  }
  __syncthreads();

  dif_pass<11>(z, tid); __syncthreads();
  dif_pass<9>(z, tid);  __syncthreads();
  dif_pass<7>(z, tid);  __syncthreads();
  dif_pass<5>(z, tid);  __syncthreads();
  dif_pass<3>(z, tid);  __syncthreads();
  dif_r8(z, tid);       __syncthreads();

  C2 P[16];
#pragma unroll
  for (int it = 0; it < 16; ++it) {
    int p = tid + it * 512;
    int k = BR13(p);
    int km = (8192 - k) & 8191;
    int p2 = BR13(km);
    C2 Zk = z[swz(p)], Zm = z[swz(p2)];
    float xr = Zk.x + Zm.x, xi2 = Zk.y - Zm.y;
    float kr = Zk.y + Zm.y, ki = Zm.x - Zk.x;
    P[it] = {xr * kr - xi2 * ki, -(xr * ki + xi2 * kr)};
  }
  __syncthreads();
#pragma unroll
  for (int it = 0; it < 16; ++it) z[swz(tid + it * 512)] = P[it];
  __syncthreads();

  dit_r8(z, tid);       __syncthreads();
  dit_pass<3>(z, tid);  __syncthreads();
  dit_pass<5>(z, tid);  __syncthreads();
  dit_pass<7>(z, tid);  __syncthreads();
  dit_pass<9>(z, tid);  __syncthreads();
  dit_pass<11>(z, tid); __syncthreads();

  const float sc = 1.0f / 32768.0f;
  u16 o[8];
#pragma unroll
  for (int e = 0; e < 8; ++e) {
    float y = z[swz(l0 + e)].x * sc;
    o[e] = f2bf(fmaf(Dh, xn8[e], y));
  }
  uint4 pk;
  pk.x = (u32)o[0] | ((u32)o[1] << 16);
  pk.y = (u32)o[2] | ((u32)o[3] << 16);
  pk.z = (u32)o[4] | ((u32)o[5] << 16);
  pk.w = (u32)o[6] | ((u32)o[7] << 16);
  *(uint4*)(dT + ((size_t)h << 13) + (b << 12) + l0) = pk;
}

// ---------------------------------------------------------------- launch
extern "C" void kernel_launch(void* const* d_in, const int* in_sizes, int n_in,
                              void* d_out, int out_size, void* d_ws, size_t ws_size,
                              hipStream_t stream) {
  (void)in_sizes; (void)n_in; (void)out_size; (void)ws_size;
  const float* idx  = (const float*)d_in[0];
  const float* n1w  = (const float*)d_in[1];
  const float* n1b  = (const float*)d_in[2];
  const float* Wxg  = (const float*)d_in[3];
  const float* Wdin = (const float*)d_in[4];
  const float* n2w  = (const float*)d_in[5];
  const float* n2b  = (const float*)d_in[6];
  const float* LR   = (const float*)d_in[7];
  const float* LI   = (const float*)d_in[8];
  const float* CR   = (const float*)d_in[9];
  const float* CI   = (const float*)d_in[10];
  const float* Dv   = (const float*)d_in[11];
  const float* Wgate= (const float*)d_in[12];
  const float* Wout = (const float*)d_in[13];
  const float* bout = (const float*)d_in[14];
  float* out = (float*)d_out;

  const int Bn = 2, L = 4096, DIM = 1024, HID = 4096, H = 512;
  const int M = Bn * L;  // 8192

  char* p = (char*)d_ws;
  auto alloc = [&](size_t bytes) { char* q = p; p += (bytes + 255) & ~(size_t)255; return q; };
  u16* Wxg_t   = (u16*)alloc((size_t)HID * DIM * 2);
  u16* Wdin_t  = (u16*)alloc((size_t)H * DIM * 2);
  u16* Wgate_t = (u16*)alloc((size_t)HID * H * 2);
  u16* Wout_t  = (u16*)alloc((size_t)DIM * HID * 2);
  u16* xbf     = (u16*)alloc((size_t)M * DIM * 2);
  u16* xg      = (u16*)alloc((size_t)M * HID * 2);    // later aliased as e
  float* xdT   = (float*)alloc((size_t)H * M * 4);    // [512][8192]
  float* meanv = (float*)alloc((size_t)M * 4);
  float* invv  = (float*)alloc((size_t)M * 4);
  u16* SRSI    = (u16*)alloc((size_t)L * 1024 * 2);
  u16* Ct      = (u16*)alloc((size_t)H * 1024 * 2);
  float* KT    = (float*)alloc((size_t)H * L * 4);    // [512][4096]
  u16* dTm     = (u16*)alloc((size_t)H * M * 2);      // d^T [512][8192]
  u16* dbuf    = (u16*)alloc((size_t)M * H * 2);      // d   [8192][512]

  // 1) weight transpose+convert
  trans_conv<<<dim3((DIM / 32) * (HID / 32)), 256, 0, stream>>>(Wxg, Wxg_t, DIM, HID);
  trans_conv<<<dim3((DIM / 32) * (H / 32)), 256, 0, stream>>>(Wdin, Wdin_t, DIM, H);
  trans_conv<<<dim3((H / 32) * (HID / 32)), 256, 0, stream>>>(Wgate, Wgate_t, H, HID);
  trans_conv<<<dim3((HID / 32) * (DIM / 32)), 256, 0, stream>>>(Wout, Wout_t, HID, DIM);
  // 2) LN1
  ln_kernel<true><<<dim3(M), 256, 0, stream>>>(idx, n1w, n1b, xbf, DIM);
  // 3) xg = x @ Wxg (bf16) — 256x256, 512 blocks
  gemm256<1, 256><<<dim3((M / 256) * (HID / 256)), 512, 0, stream>>>(
      xbf, Wxg_t, M, HID, DIM, nullptr, xg, nullptr, nullptr, nullptr);
  // 4) xd^T = Wdin_t @ xbf^T  [512][8192] f32 (small M -> 128x128, 256 blocks)
  gemm_bf16<0><<<dim3((H / 128) * (M / 128)), 256, 0, stream>>>(
      Wdin_t, xbf, H, M, DIM, xdT, nullptr, nullptr, nullptr, nullptr);
  // 5) LN2 column stats
  ln_stats<<<dim3(M / 64), 256, 0, stream>>>(xdT, meanv, invv);
  // 6) S and C generation
  kgen_s<<<dim3(L * 1024 / 256), 256, 0, stream>>>(LR, LI, SRSI);
  kgen_c<<<dim3(H * 512 / 256), 256, 0, stream>>>(LR, LI, CR, CI, Ct);
  // 7) K^T = Ct @ SRSI^T  [512][4096] f32
  gemm_bf16<0><<<dim3((H / 128) * (L / 128)), 256, 0, stream>>>(
      Ct, SRSI, H, L, 1024, KT, nullptr, nullptr, nullptr, nullptr);
  // 8) FFT causal conv (+LN2 on the fly, +D*xn) -> d^T bf16
  fft_conv2<<<dim3(Bn * H), 512, 0, stream>>>(xdT, KT, meanv, invv, n2w, n2b, Dv, dTm);
  // 8b) d^T -> d
  trans_bf<<<dim3((H / 32) * (M / 32)), 256, 0, stream>>>(dTm, dbuf, H, M);
  // 9) e = (d @ Wgate) * xg  (bf16, aliases xg) — 256x256, 512 blocks
  gemm256<2, 256><<<dim3((M / 256) * (HID / 256)), 512, 0, stream>>>(
      dbuf, Wgate_t, M, HID, H, nullptr, xg, xg, nullptr, nullptr);
  // 10) out = e @ Wout + bout + idx — 256x128, 256 blocks (fills all CUs)
  gemm256<3, 128><<<dim3((M / 256) * (DIM / 128)), 512, 0, stream>>>(
      xg, Wout_t, M, DIM, HID, out, nullptr, nullptr, bout, idx);
}

// Round 5
// 403.048 us; speedup vs baseline: 1.6136x; 1.0283x over previous
//
#include <hip/hip_runtime.h>
#include <math.h>

// GSS block on MI355X. Shapes: B=2, L=4096, DIM=1024, HID=4096, H=DSSH=512, N=DSSN=512.
// R5: FFT conv restructured: batch-packed forward (xn0 + i*xn1, one FFT per h),
// precomputed bit-rev bf16 Kf spectra (P0+i*P1 = Kf*Z identity => elementwise product),
// fused r8(DIF)+product+r8(DIT) register phase, zero-half first pass, lower-half
// last pass, float4 (w,w^2) twiddle table. GEMMs unchanged from R4.

typedef unsigned short u16;
typedef unsigned int u32;
typedef __attribute__((ext_vector_type(8))) __bf16 bf16x8;
typedef __attribute__((ext_vector_type(4))) float f32x4;

__device__ __forceinline__ u16 f2bf(float f) {
  u32 u = __float_as_uint(f);
  u32 r = u + 0x7FFFu + ((u >> 16) & 1u);
  return (u16)(r >> 16);
}
__device__ __forceinline__ float bf2f(u16 h) { return __uint_as_float(((u32)h) << 16); }

// ---------------------------------------------------------------- transpose+convert
__global__ __launch_bounds__(256) void trans_conv(
    const float* __restrict__ in, u16* __restrict__ out, int K, int N) {
  __shared__ float t[32][33];
  int tx = threadIdx.x & 31, ty = threadIdx.x >> 5;
  int nb = N >> 5;
  int k0 = (blockIdx.x / nb) << 5;
  int n0 = (blockIdx.x % nb) << 5;
#pragma unroll
  for (int i = 0; i < 32; i += 8)
    t[ty + i][tx] = in[(size_t)(k0 + ty + i) * N + n0 + tx];
  __syncthreads();
#pragma unroll
  for (int i = 0; i < 32; i += 8)
    out[(size_t)(n0 + ty + i) * K + k0 + tx] = f2bf(t[tx][ty + i]);
}

// bf16 [R][C] -> bf16 [C][R]
__global__ __launch_bounds__(256) void trans_bf(
    const u16* __restrict__ in, u16* __restrict__ out, int R, int C) {
  __shared__ u16 t[32][34];
  int tx = threadIdx.x & 31, ty = threadIdx.x >> 5;
  int nb = C >> 5;
  int r0 = (blockIdx.x / nb) << 5;
  int c0 = (blockIdx.x % nb) << 5;
#pragma unroll
  for (int i = 0; i < 32; i += 8)
    t[ty + i][tx] = in[(size_t)(r0 + ty + i) * C + c0 + tx];
  __syncthreads();
#pragma unroll
  for (int i = 0; i < 32; i += 8)
    out[(size_t)(c0 + ty + i) * R + r0 + tx] = t[tx][ty + i];
}

// ---------------------------------------------------------------- LayerNorm (LN1)
template <bool BOUT>
__global__ void ln_kernel(const float* __restrict__ in, const float* __restrict__ gw,
                          const float* __restrict__ gb, void* outp, int D) {
  int row = blockIdx.x;
  int tid = threadIdx.x;
  const float4* r4 = (const float4*)(in + (size_t)row * D);
  float4 v = r4[tid];
  float s = v.x + v.y + v.z + v.w;
  float ss = fmaf(v.x, v.x, fmaf(v.y, v.y, fmaf(v.z, v.z, v.w * v.w)));
#pragma unroll
  for (int o = 32; o >= 1; o >>= 1) { s += __shfl_xor(s, o); ss += __shfl_xor(ss, o); }
  __shared__ float sa[8], sb[8];
  int nw = blockDim.x >> 6;
  if ((tid & 63) == 0) { sa[tid >> 6] = s; sb[tid >> 6] = ss; }
  __syncthreads();
  float S = 0.f, SS = 0.f;
  for (int i = 0; i < nw; ++i) { S += sa[i]; SS += sb[i]; }
  float mean = S / (float)D;
  float var = SS / (float)D - mean * mean;
  float inv = rsqrtf(var + 1e-5f);
  float4 wv = ((const float4*)gw)[tid];
  float4 bv = ((const float4*)gb)[tid];
  float o0 = (v.x - mean) * inv * wv.x + bv.x;
  float o1 = (v.y - mean) * inv * wv.y + bv.y;
  float o2 = (v.z - mean) * inv * wv.z + bv.z;
  float o3 = (v.w - mean) * inv * wv.w + bv.w;
  if (BOUT) {
    ushort4 o; o.x = f2bf(o0); o.y = f2bf(o1); o.z = f2bf(o2); o.w = f2bf(o3);
    ((ushort4*)outp)[(size_t)row * (D >> 2) + tid] = o;
  } else {
    float4 o; o.x = o0; o.y = o1; o.z = o2; o.w = o3;
    ((float4*)outp)[(size_t)row * (D >> 2) + tid] = o;
  }
}

// ---------------------------------------------------------------- LN2 column stats
__global__ __launch_bounds__(256) void ln_stats(
    const float* __restrict__ xdT, float* __restrict__ meanv, float* __restrict__ invv) {
  int lane = threadIdx.x & 63;
  int seg = threadIdx.x >> 6;
  int col = blockIdx.x * 64 + lane;
  float s = 0.f, ss = 0.f;
  const float* p = xdT + (size_t)(seg * 128) * 8192 + col;
  for (int r = 0; r < 128; ++r) {
    float v = p[(size_t)r * 8192];
    s += v; ss = fmaf(v, v, ss);
  }
  __shared__ float sa[4][64], sb[4][64];
  sa[seg][lane] = s; sb[seg][lane] = ss;
  __syncthreads();
  if (threadIdx.x < 64) {
    float S = sa[0][lane] + sa[1][lane] + sa[2][lane] + sa[3][lane];
    float SS = sb[0][lane] + sb[1][lane] + sb[2][lane] + sb[3][lane];
    float mean = S * (1.0f / 512.0f);
    float var = SS * (1.0f / 512.0f) - mean * mean;
    meanv[blockIdx.x * 64 + lane] = mean;
    invv[blockIdx.x * 64 + lane] = rsqrtf(var + 1e-5f);
  }
}

// ---------------------------------------------------------------- 128x128 GEMM (small shapes)
template <int MODE>
__global__ __launch_bounds__(256) void gemm_bf16(
    const u16* __restrict__ A, const u16* __restrict__ Bt,
    int M, int N, int K,
    float* Cf, u16* Cb, const u16* aux,
    const float* __restrict__ bias, const float* __restrict__ res) {
  __shared__ __align__(16) u16 As[128 * 32];
  __shared__ __align__(16) u16 Bs[128 * 32];
  const int tid = threadIdx.x;
  const int lane = tid & 63;
  const int wid = tid >> 6;
  const int nwg = (int)gridDim.x;
  const int cpx = nwg >> 3;
  const int bid = ((int)blockIdx.x & 7) * cpx + ((int)blockIdx.x >> 3);
  const int tiles_n = N >> 7;
  const int tm = (bid / tiles_n) << 7;
  const int tn = (bid % tiles_n) << 7;

  const int srow = wid * 32 + (lane >> 2);
  const int scol = (lane & 3) << 3;
  const u16* gA = A + (size_t)(tm + srow) * K + scol;
  const u16* gB = Bt + (size_t)(tn + srow) * K + scol;
  const u16* gA2 = gA + (size_t)16 * K;
  const u16* gB2 = gB + (size_t)16 * K;
  auto As3 = (__attribute__((address_space(3))) char*)As;
  auto Bs3 = (__attribute__((address_space(3))) char*)Bs;
  const u32 lds0 = (u32)wid * 2048u;
  const u32 lds1 = lds0 + 1024u;

  const int lr = lane & 15;
  const int kq = lane >> 4;
  const int wr = (wid >> 1) * 64;
  const int wc = (wid & 1) * 64;

  f32x4 acc[4][4] = {};

  for (int k0 = 0; k0 < K; k0 += 32) {
    __builtin_amdgcn_global_load_lds((const __attribute__((address_space(1))) void*)(gA + k0),
                                     (__attribute__((address_space(3))) void*)(As3 + lds0), 16, 0, 0);
    __builtin_amdgcn_global_load_lds((const __attribute__((address_space(1))) void*)(gA2 + k0),
                                     (__attribute__((address_space(3))) void*)(As3 + lds1), 16, 0, 0);
    __builtin_amdgcn_global_load_lds((const __attribute__((address_space(1))) void*)(gB + k0),
                                     (__attribute__((address_space(3))) void*)(Bs3 + lds0), 16, 0, 0);
    __builtin_amdgcn_global_load_lds((const __attribute__((address_space(1))) void*)(gB2 + k0),
                                     (__attribute__((address_space(3))) void*)(Bs3 + lds1), 16, 0, 0);
    __syncthreads();
    bf16x8 af[4], bfr[4];
#pragma unroll
    for (int mi = 0; mi < 4; ++mi)
      af[mi] = *(const bf16x8*)(As + (wr + mi * 16 + lr) * 32 + kq * 8);
#pragma unroll
    for (int ni = 0; ni < 4; ++ni)
      bfr[ni] = *(const bf16x8*)(Bs + (wc + ni * 16 + lr) * 32 + kq * 8);
#pragma unroll
    for (int mi = 0; mi < 4; ++mi)
#pragma unroll
      for (int ni = 0; ni < 4; ++ni)
        acc[mi][ni] = __builtin_amdgcn_mfma_f32_16x16x32_bf16(af[mi], bfr[ni], acc[mi][ni], 0, 0, 0);
    __syncthreads();
  }

  const int orow = tm + wr + kq * 4;
  const int ocol = tn + wc + lr;
#pragma unroll
  for (int mi = 0; mi < 4; ++mi)
#pragma unroll
    for (int ni = 0; ni < 4; ++ni)
#pragma unroll
      for (int j = 0; j < 4; ++j) {
        int r = orow + mi * 16 + j;
        int c = ocol + ni * 16;
        size_t off = (size_t)r * N + c;
        float v = acc[mi][ni][j];
        if (MODE == 0) Cf[off] = v;
        else if (MODE == 1) Cb[off] = f2bf(v);
        else if (MODE == 2) Cb[off] = f2bf(v * bf2f(aux[off]));
        else Cf[off] = v + bias[c] + res[off];
      }
}

// ---------------------------------------------------------------- 256xBN 8-wave GEMM
template <int MODE, int BN>
__global__ __launch_bounds__(512, 2) void gemm256(
    const u16* __restrict__ A, const u16* __restrict__ Bt,
    int M, int N, int K,
    float* Cf, u16* Cb, const u16* aux,
    const float* __restrict__ bias, const float* __restrict__ res) {
  constexpr int BM = 256;
  constexpr int WN = BN / 64;
  constexpr int WM = 8 / WN;
  constexpr int MI = BM / WM / 16;
  constexpr int NI = 4;
  constexpr int LA = BM / 64;
  constexpr int LB = BN / 64;
  constexpr int ASZ = BM * 64;
  constexpr int BUF = ASZ + BN * 64;
  __shared__ __align__(16) u16 lds[2 * BUF];

  const int tid = threadIdx.x;
  const int lane = tid & 63;
  const int w = tid >> 6;
  const int nwg = (int)gridDim.x;
  const int cpx = nwg >> 3;
  const int bid = ((int)blockIdx.x & 7) * cpx + ((int)blockIdx.x >> 3);
  const int tiles_n = N / BN;
  const int tm = (bid / tiles_n) * BM;
  const int tn = (bid % tiles_n) * BN;

  const int wm = w / WN;
  const int wn = w % WN;
  const int lr = lane & 15;
  const int kq = lane >> 4;
  const int l7 = lane & 7;

  const int rsub = lane >> 3;
  const int sslot = (lane & 7) ^ rsub;
  const u16* gA = A + (size_t)(tm + w * (BM / 8) + rsub) * K + sslot * 8;
  const u16* gB = Bt + (size_t)(tn + w * (BN / 8) + rsub) * K + sslot * 8;
  auto ldsc = (__attribute__((address_space(3))) char*)lds;

  auto STAGE = [&](int kt, int c) {
    const size_t kof = (size_t)kt << 6;
#pragma unroll
    for (int i = 0; i < LA; ++i) {
      u32 dst = (u32)(c * BUF + (w * (BM / 8) + i * 8) * 64) * 2u;
      __builtin_amdgcn_global_load_lds(
          (const __attribute__((address_space(1))) void*)(gA + (size_t)(i * 8) * K + kof),
          (__attribute__((address_space(3))) void*)(ldsc + dst), 16, 0, 0);
    }
#pragma unroll
    for (int i = 0; i < LB; ++i) {
      u32 dst = (u32)(c * BUF + ASZ + (w * (BN / 8) + i * 8) * 64) * 2u;
      __builtin_amdgcn_global_load_lds(
          (const __attribute__((address_space(1))) void*)(gB + (size_t)(i * 8) * K + kof),
          (__attribute__((address_space(3))) void*)(ldsc + dst), 16, 0, 0);
    }
  };

  f32x4 acc[MI][NI] = {};
  const int NT = K >> 6;

  STAGE(0, 0);
  asm volatile("s_waitcnt vmcnt(0)" ::: "memory");
  __builtin_amdgcn_s_barrier();
  __builtin_amdgcn_sched_barrier(0);

  int cur = 0;
  for (int kt = 0; kt < NT; ++kt) {
    if (kt + 1 < NT) STAGE(kt + 1, cur ^ 1);
    const u32 ab = (u32)cur * BUF;
#pragma unroll
    for (int ks = 0; ks < 2; ++ks) {
      const int slp = ((((ks << 2) | kq)) ^ l7) << 3;
      bf16x8 af[MI], bv[NI];
#pragma unroll
      for (int mi = 0; mi < MI; ++mi) {
        int ra = wm * (MI * 16) + mi * 16 + lr;
        af[mi] = *(const bf16x8*)&lds[ab + ra * 64 + slp];
      }
#pragma unroll
      for (int ni = 0; ni < NI; ++ni) {
        int rb = wn * 64 + ni * 16 + lr;
        bv[ni] = *(const bf16x8*)&lds[ab + ASZ + rb * 64 + slp];
      }
      __builtin_amdgcn_s_setprio(1);
#pragma unroll
      for (int mi = 0; mi < MI; ++mi)
#pragma unroll
        for (int ni = 0; ni < NI; ++ni)
          acc[mi][ni] = __builtin_amdgcn_mfma_f32_16x16x32_bf16(af[mi], bv[ni], acc[mi][ni], 0, 0, 0);
      __builtin_amdgcn_s_setprio(0);
    }
    asm volatile("s_waitcnt vmcnt(0)" ::: "memory");
    __builtin_amdgcn_s_barrier();
    __builtin_amdgcn_sched_barrier(0);
    cur ^= 1;
  }

  const int orow0 = tm + wm * (MI * 16) + kq * 4;
  const int ocol0 = tn + wn * 64 + lr;
#pragma unroll
  for (int mi = 0; mi < MI; ++mi)
#pragma unroll
    for (int ni = 0; ni < NI; ++ni)
#pragma unroll
      for (int j = 0; j < 4; ++j) {
        int r = orow0 + mi * 16 + j;
        int cc = ocol0 + ni * 16;
        size_t off = (size_t)r * N + cc;
        float v = acc[mi][ni][j];
        if (MODE == 1) Cb[off] = f2bf(v);
        else if (MODE == 2) Cb[off] = f2bf(v * bf2f(aux[off]));
        else Cf[off] = v + bias[cc] + res[off];
      }
}

// ---------------------------------------------------------------- DSS kernel generation
__global__ __launch_bounds__(256) void kgen_s(
    const float* __restrict__ LR, const float* __restrict__ LI, u16* __restrict__ SRSI) {
  int idx0 = blockIdx.x * 256 + threadIdx.x;
  int l = idx0 >> 10;
  int kk = idx0 & 1023;
  int n = kk & 511;
  double a = exp((double)LR[n]);
  double om = exp((double)LI[n]);
  double ld = (double)l;
  float decay = (float)exp(-a * ld);
  double th = fmod(om * ld, 6.283185307179586477);
  float c, s;
  sincosf((float)th, &s, &c);
  SRSI[idx0] = f2bf(decay * ((kk < 512) ? c : s));
}

__global__ __launch_bounds__(256) void kgen_c(
    const float* __restrict__ LR, const float* __restrict__ LI,
    const float* __restrict__ CR, const float* __restrict__ CI, u16* __restrict__ Ct) {
  int idx0 = blockIdx.x * 256 + threadIdx.x;  // over 512*512
  int h = idx0 >> 9, n = idx0 & 511;
  float eLR = expf(LR[n]), eLI = expf(LI[n]);
  float lre = -eLR, lim = eLI;
  float er = expf(lre);
  float c, s;
  sincosf(lim, &s, &c);
  float wr = er * c - 1.0f, wi = er * s;
  float den = lre * lre + lim * lim;
  float gr = (wr * lre + wi * lim) / den;
  float gi = (wi * lre - wr * lim) / den;
  float cr = CR[(size_t)h * 512 + n], ci = CI[(size_t)h * 512 + n];
  float ccr = cr * gr - ci * gi;
  float cci = cr * gi + ci * gr;
  Ct[(size_t)h * 1024 + n] = f2bf(ccr);
  Ct[(size_t)h * 1024 + 512 + n] = f2bf(-cci);
}

// ---------------------------------------------------------------- twiddle table
// twg4[j] = (cos t, sin t, cos 2t, sin 2t), t = -2*pi*j/8192, j < 2048.
__global__ __launch_bounds__(256) void twfill(float4* __restrict__ twg4) {
  int j = blockIdx.x * 256 + threadIdx.x;
  float t1 = -6.2831853071795864769f * (float)j / 8192.0f;
  float s1, c1, s2, c2;
  sincosf(t1, &s1, &c1);
  sincosf(2.0f * t1, &s2, &c2);
  twg4[j] = {c1, s1, c2, s2};
}

// ---------------------------------------------------------------- FFT machinery
struct C2 { float x, y; };
__device__ __forceinline__ C2 cadd(C2 a, C2 b) { return {a.x + b.x, a.y + b.y}; }
__device__ __forceinline__ C2 csub(C2 a, C2 b) { return {a.x - b.x, a.y - b.y}; }
__device__ __forceinline__ C2 cmul(C2 a, C2 b) {
  return {a.x * b.x - a.y * b.y, a.x * b.y + a.y * b.x};
}
__device__ __forceinline__ C2 cmulni(C2 a) { return {a.y, -a.x}; }  // * (-i)

__device__ __forceinline__ int swz(int a) {
  return a ^ ((a >> 7) & 15) ^ ((a >> 11) & 3) ^ ((a >> 2) & 8) ^ ((a >> 3) & 2) ^ ((a >> 4) & 4);
}

#define BR13(x) ((int)(__brev((u32)(x)) >> 19))
#define RS 0.70710678118654752f

// First DIF pass specialized for zero upper half: reads only z[0..4096).
__device__ __forceinline__ void dif_pass11z(C2* z, int tid, const float4* __restrict__ twg4) {
#pragma unroll
  for (int j = 0; j < 4; ++j) {
    int i0 = tid + j * 512;  // pos = i0 in [0,2048)
    int ia = swz(i0), ib = swz(i0 + 2048), ic = swz(i0 + 4096), id = swz(i0 + 6144);
    C2 a = z[ia], bb = z[ib];
    float4 wv = twg4[i0];
    C2 w = {wv.x, wv.y};
    C2 wm = {wv.y, -wv.x};
    C2 w2 = {wv.z, wv.w};
    C2 aw = cmul(a, w);
    C2 bw = cmul(bb, wm);
    z[ia] = cadd(a, bb);
    z[ib] = cmul(csub(a, bb), w2);
    z[ic] = cadd(aw, bw);
    z[id] = cmul(csub(aw, bw), w2);
  }
}

template <int LOGM>
__device__ __forceinline__ void dif_pass(C2* z, int tid, const float4* __restrict__ twg4) {
  const int M4 = 1 << LOGM;
#pragma unroll
  for (int j = 0; j < 4; ++j) {
    int b = tid + j * 512;
    int pos = b & (M4 - 1);
    int i0 = ((b >> LOGM) << (LOGM + 2)) | pos;
    int ia = swz(i0), ib = swz(i0 + M4), ic = swz(i0 + 2 * M4), id = swz(i0 + 3 * M4);
    C2 a = z[ia], bb = z[ib], c = z[ic], d = z[id];
    float4 wv = twg4[pos << (11 - LOGM)];
    C2 w = {wv.x, wv.y};
    C2 wm = {wv.y, -wv.x};
    C2 w2 = {wv.z, wv.w};
    C2 a1 = cadd(a, c);
    C2 c1 = cmul(csub(a, c), w);
    C2 b1 = cadd(bb, d);
    C2 d1 = cmul(csub(bb, d), wm);
    z[ia] = cadd(a1, b1);
    z[ib] = cmul(csub(a1, b1), w2);
    z[ic] = cadd(c1, d1);
    z[id] = cmul(csub(c1, d1), w2);
  }
}

template <int LOGM>
__device__ __forceinline__ void dit_pass(C2* z, int tid, const float4* __restrict__ twg4) {
  const int M4 = 1 << LOGM;
#pragma unroll
  for (int j = 0; j < 4; ++j) {
    int b = tid + j * 512;
    int pos = b & (M4 - 1);
    int i0 = ((b >> LOGM) << (LOGM + 2)) | pos;
    int ia = swz(i0), ib = swz(i0 + M4), ic = swz(i0 + 2 * M4), id = swz(i0 + 3 * M4);
    C2 a = z[ia], bb = z[ib], c = z[ic], d = z[id];
    float4 wv = twg4[pos << (11 - LOGM)];
    C2 w = {wv.x, wv.y};
    C2 wm = {wv.y, -wv.x};
    C2 wa = {wv.z, wv.w};
    C2 t = cmul(wa, bb);
    C2 a1 = cadd(a, t), b1 = csub(a, t);
    C2 u = cmul(wa, d);
    C2 c1 = cadd(c, u), d1 = csub(c, u);
    C2 v = cmul(w, c1);
    C2 xx = cmul(wm, d1);
    z[ia] = cadd(a1, v);
    z[ic] = csub(a1, v);
    z[ib] = cadd(b1, xx);
    z[id] = csub(b1, xx);
  }
}

// Last DIT pass: only outputs n < 4096 (ia=i0, ib=i0+2048) are needed.
__device__ __forceinline__ void dit_pass11_last(C2* z, int tid, const float4* __restrict__ twg4) {
#pragma unroll
  for (int j = 0; j < 4; ++j) {
    int i0 = tid + j * 512;  // pos = i0 in [0,2048)
    int ia = swz(i0), ib = swz(i0 + 2048), ic = swz(i0 + 4096), id = swz(i0 + 6144);
    C2 a = z[ia], bb = z[ib], c = z[ic], d = z[id];
    float4 wv = twg4[i0];
    C2 w = {wv.x, wv.y};
    C2 wm = {wv.y, -wv.x};
    C2 wa = {wv.z, wv.w};
    C2 t = cmul(wa, bb);
    C2 a1 = cadd(a, t), b1 = csub(a, t);
    C2 u = cmul(wa, d);
    C2 c1 = cadd(c, u), d1 = csub(c, u);
    z[ia] = cadd(a1, cmul(w, c1));
    z[ib] = cadd(b1, cmul(wm, d1));
  }
}

// Register radix-8 DIF (spans 4,2,1) — used by kfft.
__device__ __forceinline__ void dif_r8(C2* z, int tid) {
#pragma unroll
  for (int j = 0; j < 2; ++j) {
    int base = (tid + j * 512) << 3;
    int ad[8]; C2 x[8];
#pragma unroll
    for (int e = 0; e < 8; ++e) { ad[e] = swz(base + e); x[e] = z[ad[e]]; }
    C2 t;
    t = csub(x[0], x[4]); x[0] = cadd(x[0], x[4]); x[4] = t;
    t = csub(x[1], x[5]); x[1] = cadd(x[1], x[5]); x[5] = cmul(t, {RS, -RS});
    t = csub(x[2], x[6]); x[2] = cadd(x[2], x[6]); x[6] = cmulni(t);
    t = csub(x[3], x[7]); x[3] = cadd(x[3], x[7]); x[7] = cmul(t, {-RS, -RS});
    t = csub(x[0], x[2]); x[0] = cadd(x[0], x[2]); x[2] = t;
    t = csub(x[1], x[3]); x[1] = cadd(x[1], x[3]); x[3] = cmulni(t);
    t = csub(x[4], x[6]); x[4] = cadd(x[4], x[6]); x[6] = t;
    t = csub(x[5], x[7]); x[5] = cadd(x[5], x[7]); x[7] = cmulni(t);
    t = csub(x[0], x[1]); x[0] = cadd(x[0], x[1]); x[1] = t;
    t = csub(x[2], x[3]); x[2] = cadd(x[2], x[3]); x[3] = t;
    t = csub(x[4], x[5]); x[4] = cadd(x[4], x[5]); x[5] = t;
    t = csub(x[6], x[7]); x[6] = cadd(x[6], x[7]); x[7] = t;
#pragma unroll
    for (int e = 0; e < 8; ++e) z[ad[e]] = x[e];
  }
}

// Fused: DIF r8 (spans 4,2,1) -> elementwise *Kf (bf16-packed) + conj -> DIT r8
// (spans 1,2,4). Same thread owns all 16 elements across all three phases.
__device__ __forceinline__ void r8_fused(C2* z, int tid, const u32* __restrict__ kfr) {
#pragma unroll
  for (int j = 0; j < 2; ++j) {
    int base = (tid + j * 512) << 3;
    int ad[8]; C2 x[8];
#pragma unroll
    for (int e = 0; e < 8; ++e) { ad[e] = swz(base + e); x[e] = z[ad[e]]; }
    uint4 k0 = *(const uint4*)(kfr + base);
    uint4 k1 = *(const uint4*)(kfr + base + 4);
    u32 kw[8] = {k0.x, k0.y, k0.z, k0.w, k1.x, k1.y, k1.z, k1.w};
    C2 t;
    // DIF spans 4,2,1
    t = csub(x[0], x[4]); x[0] = cadd(x[0], x[4]); x[4] = t;
    t = csub(x[1], x[5]); x[1] = cadd(x[1], x[5]); x[5] = cmul(t, {RS, -RS});
    t = csub(x[2], x[6]); x[2] = cadd(x[2], x[6]); x[6] = cmulni(t);
    t = csub(x[3], x[7]); x[3] = cadd(x[3], x[7]); x[7] = cmul(t, {-RS, -RS});
    t = csub(x[0], x[2]); x[0] = cadd(x[0], x[2]); x[2] = t;
    t = csub(x[1], x[3]); x[1] = cadd(x[1], x[3]); x[3] = cmulni(t);
    t = csub(x[4], x[6]); x[4] = cadd(x[4], x[6]); x[6] = t;
    t = csub(x[5], x[7]); x[5] = cadd(x[5], x[7]); x[7] = cmulni(t);
    t = csub(x[0], x[1]); x[0] = cadd(x[0], x[1]); x[1] = t;
    t = csub(x[2], x[3]); x[2] = cadd(x[2], x[3]); x[3] = t;
    t = csub(x[4], x[5]); x[4] = cadd(x[4], x[5]); x[5] = t;
    t = csub(x[6], x[7]); x[6] = cadd(x[6], x[7]); x[7] = t;
    // P = Z*Kf; keep conj(P)
#pragma unroll
    for (int e = 0; e < 8; ++e) {
      C2 kf = {bf2f((u16)(kw[e] & 0xffffu)), bf2f((u16)(kw[e] >> 16))};
      C2 pr = cmul(x[e], kf);
      x[e] = {pr.x, -pr.y};
    }
    // DIT spans 1,2,4
    t = x[1]; x[1] = csub(x[0], t); x[0] = cadd(x[0], t);
    t = x[3]; x[3] = csub(x[2], t); x[2] = cadd(x[2], t);
    t = x[5]; x[5] = csub(x[4], t); x[4] = cadd(x[4], t);
    t = x[7]; x[7] = csub(x[6], t); x[6] = cadd(x[6], t);
    t = x[2];          x[2] = csub(x[0], t); x[0] = cadd(x[0], t);
    t = cmulni(x[3]);  x[3] = csub(x[1], t); x[1] = cadd(x[1], t);
    t = x[6];          x[6] = csub(x[4], t); x[4] = cadd(x[4], t);
    t = cmulni(x[7]);  x[7] = csub(x[5], t); x[5] = cadd(x[5], t);
    t = x[4];                    x[4] = csub(x[0], t); x[0] = cadd(x[0], t);
    t = cmul(x[5], {RS, -RS});   x[5] = csub(x[1], t); x[1] = cadd(x[1], t);
    t = cmulni(x[6]);            x[6] = csub(x[2], t); x[2] = cadd(x[2], t);
    t = cmul(x[7], {-RS, -RS});  x[7] = csub(x[3], t); x[3] = cadd(x[3], t);
#pragma unroll
    for (int e = 0; e < 8; ++e) z[ad[e]] = x[e];
  }
}

// ---------------------------------------------------------------- K-spectrum kernel
// Block g: FFT(K[2g] + i*K[2g+1]) (8192, zero-padded), Hermitian split, store
// both spectra bf16-packed in BIT-REV order: Kfb[h][p] = pack(Kf_h[BR13(p)]).
__global__ __launch_bounds__(512) void kfft(
    const float* __restrict__ KT, const float4* __restrict__ twg4,
    u32* __restrict__ Kfb) {
  __shared__ C2 z[8192];
  const int g = blockIdx.x;
  const int tid = threadIdx.x;
  const float* k0r = KT + ((size_t)(2 * g) << 12);
  const float* k1r = KT + ((size_t)(2 * g + 1) << 12);
  const int l0 = tid << 3;
  float a0[8], a1[8];
  *(float4*)&a0[0] = *(const float4*)(k0r + l0);
  *(float4*)&a0[4] = *(const float4*)(k0r + l0 + 4);
  *(float4*)&a1[0] = *(const float4*)(k1r + l0);
  *(float4*)&a1[4] = *(const float4*)(k1r + l0 + 4);
#pragma unroll
  for (int e = 0; e < 8; ++e) z[swz(l0 + e)] = {a0[e], a1[e]};
  __syncthreads();

  dif_pass11z(z, tid, twg4); __syncthreads();
  dif_pass<9>(z, tid, twg4); __syncthreads();
  dif_pass<7>(z, tid, twg4); __syncthreads();
  dif_pass<5>(z, tid, twg4); __syncthreads();
  dif_pass<3>(z, tid, twg4); __syncthreads();
  dif_r8(z, tid);            __syncthreads();

  u32* o0 = Kfb + ((size_t)(2 * g) << 13);
  u32* o1 = Kfb + ((size_t)(2 * g + 1) << 13);
#pragma unroll
  for (int it = 0; it < 16; ++it) {
    int p = tid + it * 512;
    int k = BR13(p);
    int km = (8192 - k) & 8191;
    int p2 = BR13(km);
    C2 Zk = z[swz(p)], Zm = z[swz(p2)];
    float f0r = 0.5f * (Zk.x + Zm.x), f0i = 0.5f * (Zk.y - Zm.y);
    float f1r = 0.5f * (Zk.y + Zm.y), f1i = 0.5f * (Zm.x - Zk.x);
    o0[p] = (u32)f2bf(f0r) | ((u32)f2bf(f0i) << 16);
    o1[p] = (u32)f2bf(f1r) | ((u32)f2bf(f1i) << 16);
  }
}

// ---------------------------------------------------------------- main FFT conv
// Block h: z = LN2(xdT[h][0:4096]) + i*LN2(xdT[h][4096:8192]); forward DIF;
// z *= Kf[h] elementwise (P0+i*P1 = Kf*Z identity); conj; forward DIT;
// y0 = Re/8192, y1 = -Im/8192; dT[h] = bf16(y_b + D[h]*xn_b).
__global__ __launch_bounds__(512) void fft_conv3(
    const float* __restrict__ xdT, const u32* __restrict__ Kfb,
    const float* __restrict__ meanv, const float* __restrict__ invv,
    const float* __restrict__ n2w, const float* __restrict__ n2b,
    const float* __restrict__ Dv, const float4* __restrict__ twg4,
    u16* __restrict__ dT) {
  __shared__ C2 z[8192];
  const int h = blockIdx.x;
  const int tid = threadIdx.x;
  const float* xr = xdT + ((size_t)h << 13);
  const float w2h = n2w[h], b2h = n2b[h], Dh = Dv[h];
  const int l0 = tid << 3;

  float xv[8], mv[8], iv[8], xn0[8], xn1[8];
  *(float4*)&xv[0] = *(const float4*)(xr + l0);
  *(float4*)&xv[4] = *(const float4*)(xr + l0 + 4);
  *(float4*)&mv[0] = *(const float4*)(meanv + l0);
  *(float4*)&mv[4] = *(const float4*)(meanv + l0 + 4);
  *(float4*)&iv[0] = *(const float4*)(invv + l0);
  *(float4*)&iv[4] = *(const float4*)(invv + l0 + 4);
#pragma unroll
  for (int e = 0; e < 8; ++e) xn0[e] = (xv[e] - mv[e]) * iv[e] * w2h + b2h;
  *(float4*)&xv[0] = *(const float4*)(xr + 4096 + l0);
  *(float4*)&xv[4] = *(const float4*)(xr + 4096 + l0 + 4);
  *(float4*)&mv[0] = *(const float4*)(meanv + 4096 + l0);
  *(float4*)&mv[4] = *(const float4*)(meanv + 4096 + l0 + 4);
  *(float4*)&iv[0] = *(const float4*)(invv + 4096 + l0);
  *(float4*)&iv[4] = *(const float4*)(invv + 4096 + l0 + 4);
#pragma unroll
  for (int e = 0; e < 8; ++e) xn1[e] = (xv[e] - mv[e]) * iv[e] * w2h + b2h;
#pragma unroll
  for (int e = 0; e < 8; ++e) z[swz(l0 + e)] = {xn0[e], xn1[e]};
  __syncthreads();

  dif_pass11z(z, tid, twg4); __syncthreads();
  dif_pass<9>(z, tid, twg4); __syncthreads();
  dif_pass<7>(z, tid, twg4); __syncthreads();
  dif_pass<5>(z, tid, twg4); __syncthreads();
  dif_pass<3>(z, tid, twg4); __syncthreads();
  r8_fused(z, tid, Kfb + ((size_t)h << 13)); __syncthreads();
  dit_pass<3>(z, tid, twg4); __syncthreads();
  dit_pass<5>(z, tid, twg4); __syncthreads();
  dit_pass<7>(z, tid, twg4); __syncthreads();
  dit_pass<9>(z, tid, twg4); __syncthreads();
  dit_pass11_last(z, tid, twg4); __syncthreads();

  const float sc = 1.0f / 8192.0f;
  u16 o0[8], o1[8];
#pragma unroll
  for (int e = 0; e < 8; ++e) {
    C2 v = z[swz(l0 + e)];
    o0[e] = f2bf(fmaf(Dh, xn0[e], v.x * sc));
    o1[e] = f2bf(fmaf(Dh, xn1[e], -v.y * sc));
  }
  uint4 p0, p1;
  p0.x = (u32)o0[0] | ((u32)o0[1] << 16);
  p0.y = (u32)o0[2] | ((u32)o0[3] << 16);
  p0.z = (u32)o0[4] | ((u32)o0[5] << 16);
  p0.w = (u32)o0[6] | ((u32)o0[7] << 16);
  p1.x = (u32)o1[0] | ((u32)o1[1] << 16);
  p1.y = (u32)o1[2] | ((u32)o1[3] << 16);
  p1.z = (u32)o1[4] | ((u32)o1[5] << 16);
  p1.w = (u32)o1[6] | ((u32)o1[7] << 16);
  *(uint4*)(dT + ((size_t)h << 13) + l0) = p0;
  *(uint4*)(dT + ((size_t)h << 13) + 4096 + l0) = p1;
}

// ---------------------------------------------------------------- launch
extern "C" void kernel_launch(void* const* d_in, const int* in_sizes, int n_in,
                              void* d_out, int out_size, void* d_ws, size_t ws_size,
                              hipStream_t stream) {
  (void)in_sizes; (void)n_in; (void)out_size; (void)ws_size;
  const float* idx  = (const float*)d_in[0];
  const float* n1w  = (const float*)d_in[1];
  const float* n1b  = (const float*)d_in[2];
  const float* Wxg  = (const float*)d_in[3];
  const float* Wdin = (const float*)d_in[4];
  const float* n2w  = (const float*)d_in[5];
  const float* n2b  = (const float*)d_in[6];
  const float* LR   = (const float*)d_in[7];
  const float* LI   = (const float*)d_in[8];
  const float* CR   = (const float*)d_in[9];
  const float* CI   = (const float*)d_in[10];
  const float* Dv   = (const float*)d_in[11];
  const float* Wgate= (const float*)d_in[12];
  const float* Wout = (const float*)d_in[13];
  const float* bout = (const float*)d_in[14];
  float* out = (float*)d_out;

  const int Bn = 2, L = 4096, DIM = 1024, HID = 4096, H = 512;
  const int M = Bn * L;  // 8192

  char* p = (char*)d_ws;
  auto alloc = [&](size_t bytes) { char* q = p; p += (bytes + 255) & ~(size_t)255; return q; };
  u16* Wxg_t   = (u16*)alloc((size_t)HID * DIM * 2);
  u16* Wdin_t  = (u16*)alloc((size_t)H * DIM * 2);
  u16* Wgate_t = (u16*)alloc((size_t)HID * H * 2);
  u16* Wout_t  = (u16*)alloc((size_t)DIM * HID * 2);
  u16* xbf     = (u16*)alloc((size_t)M * DIM * 2);    // 16 MB; reused as Kfb after step 4
  u16* xg      = (u16*)alloc((size_t)M * HID * 2);    // later aliased as e
  float* xdT   = (float*)alloc((size_t)H * M * 4);    // [512][8192]
  float* meanv = (float*)alloc((size_t)M * 4);
  float* invv  = (float*)alloc((size_t)M * 4);
  u16* SRSI    = (u16*)alloc((size_t)L * 1024 * 2);
  u16* Ct      = (u16*)alloc((size_t)H * 1024 * 2);
  float* KT    = (float*)alloc((size_t)H * L * 4);    // [512][4096]
  u16* dTm     = (u16*)alloc((size_t)H * M * 2);      // d^T [512][8192]
  u16* dbuf    = (u16*)alloc((size_t)M * H * 2);      // d   [8192][512]
  float4* twg4 = (float4*)alloc((size_t)2048 * 16);   // twiddle table
  u32* Kfb = (u32*)xbf;  // [512][8192] u32 (bf16 pair), alias: xbf dead after step 4

  // 1) weight transpose+convert + twiddle table
  trans_conv<<<dim3((DIM / 32) * (HID / 32)), 256, 0, stream>>>(Wxg, Wxg_t, DIM, HID);
  trans_conv<<<dim3((DIM / 32) * (H / 32)), 256, 0, stream>>>(Wdin, Wdin_t, DIM, H);
  trans_conv<<<dim3((H / 32) * (HID / 32)), 256, 0, stream>>>(Wgate, Wgate_t, H, HID);
  trans_conv<<<dim3((HID / 32) * (DIM / 32)), 256, 0, stream>>>(Wout, Wout_t, HID, DIM);
  twfill<<<dim3(8), 256, 0, stream>>>(twg4);
  // 2) LN1
  ln_kernel<true><<<dim3(M), 256, 0, stream>>>(idx, n1w, n1b, xbf, DIM);
  // 3) xg = x @ Wxg (bf16)
  gemm256<1, 256><<<dim3((M / 256) * (HID / 256)), 512, 0, stream>>>(
      xbf, Wxg_t, M, HID, DIM, nullptr, xg, nullptr, nullptr, nullptr);
  // 4) xd^T = Wdin_t @ xbf^T  [512][8192] f32
  gemm_bf16<0><<<dim3((H / 128) * (M / 128)), 256, 0, stream>>>(
      Wdin_t, xbf, H, M, DIM, xdT, nullptr, nullptr, nullptr, nullptr);
  // 5) LN2 column stats
  ln_stats<<<dim3(M / 64), 256, 0, stream>>>(xdT, meanv, invv);
  // 6) S and C generation
  kgen_s<<<dim3(L * 1024 / 256), 256, 0, stream>>>(LR, LI, SRSI);
  kgen_c<<<dim3(H * 512 / 256), 256, 0, stream>>>(LR, LI, CR, CI, Ct);
  // 7) K^T = Ct @ SRSI^T  [512][4096] f32
  gemm_bf16<0><<<dim3((H / 128) * (L / 128)), 256, 0, stream>>>(
      Ct, SRSI, H, L, 1024, KT, nullptr, nullptr, nullptr, nullptr);
  // 7b) Kf spectra (bit-rev bf16), 256 blocks
  kfft<<<dim3(H / 2), 512, 0, stream>>>(KT, twg4, Kfb);
  // 8) packed FFT conv (+LN2 on the fly, +D*xn) -> d^T bf16, 512 blocks
  fft_conv3<<<dim3(H), 512, 0, stream>>>(xdT, Kfb, meanv, invv, n2w, n2b, Dv, twg4, dTm);
  // 8b) d^T -> d
  trans_bf<<<dim3((H / 32) * (M / 32)), 256, 0, stream>>>(dTm, dbuf, H, M);
  // 9) e = (d @ Wgate) * xg  (bf16, aliases xg)
  gemm256<2, 256><<<dim3((M / 256) * (HID / 256)), 512, 0, stream>>>(
      dbuf, Wgate_t, M, HID, H, nullptr, xg, xg, nullptr, nullptr);
  // 10) out = e @ Wout + bout + idx
  gemm256<3, 128><<<dim3((M / 256) * (DIM / 128)), 512, 0, stream>>>(
      xg, Wout_t, M, DIM, HID, out, nullptr, nullptr, bout, idx);
}

// Round 6
// 357.770 us; speedup vs baseline: 1.8178x; 1.1266x over previous
//
#include <hip/hip_runtime.h>
#include <math.h>

// GSS block on MI355X. Shapes: B=2, L=4096, DIM=1024, HID=4096, H=DSSH=512, N=DSSN=512.
// R6: single unified GEMM kernel gemm128p: 128x128 tile, 4 waves, BK=64, 2-phase
// schedule (STAGE-early, one vmcnt(0)+barrier per K-tile), XOR slot swizzle,
// LDS-shuffle vectorized epilogue (uint4 stores, coalesced aux loads).
// xd^T and K^T intermediates now bf16. FFT pipeline as R5.

typedef unsigned short u16;
typedef unsigned int u32;
typedef __attribute__((ext_vector_type(8))) __bf16 bf16x8;
typedef __attribute__((ext_vector_type(4))) float f32x4;

__device__ __forceinline__ u16 f2bf(float f) {
  u32 u = __float_as_uint(f);
  u32 r = u + 0x7FFFu + ((u >> 16) & 1u);
  return (u16)(r >> 16);
}
__device__ __forceinline__ float bf2f(u16 h) { return __uint_as_float(((u32)h) << 16); }

// ---------------------------------------------------------------- transpose+convert
__global__ __launch_bounds__(256) void trans_conv(
    const float* __restrict__ in, u16* __restrict__ out, int K, int N) {
  __shared__ float t[32][33];
  int tx = threadIdx.x & 31, ty = threadIdx.x >> 5;
  int nb = N >> 5;
  int k0 = (blockIdx.x / nb) << 5;
  int n0 = (blockIdx.x % nb) << 5;
#pragma unroll
  for (int i = 0; i < 32; i += 8)
    t[ty + i][tx] = in[(size_t)(k0 + ty + i) * N + n0 + tx];
  __syncthreads();
#pragma unroll
  for (int i = 0; i < 32; i += 8)
    out[(size_t)(n0 + ty + i) * K + k0 + tx] = f2bf(t[tx][ty + i]);
}

// bf16 [R][C] -> bf16 [C][R]
__global__ __launch_bounds__(256) void trans_bf(
    const u16* __restrict__ in, u16* __restrict__ out, int R, int C) {
  __shared__ u16 t[32][34];
  int tx = threadIdx.x & 31, ty = threadIdx.x >> 5;
  int nb = C >> 5;
  int r0 = (blockIdx.x / nb) << 5;
  int c0 = (blockIdx.x % nb) << 5;
#pragma unroll
  for (int i = 0; i < 32; i += 8)
    t[ty + i][tx] = in[(size_t)(r0 + ty + i) * C + c0 + tx];
  __syncthreads();
#pragma unroll
  for (int i = 0; i < 32; i += 8)
    out[(size_t)(c0 + ty + i) * R + r0 + tx] = t[tx][ty + i];
}

// ---------------------------------------------------------------- LayerNorm (LN1)
template <bool BOUT>
__global__ void ln_kernel(const float* __restrict__ in, const float* __restrict__ gw,
                          const float* __restrict__ gb, void* outp, int D) {
  int row = blockIdx.x;
  int tid = threadIdx.x;
  const float4* r4 = (const float4*)(in + (size_t)row * D);
  float4 v = r4[tid];
  float s = v.x + v.y + v.z + v.w;
  float ss = fmaf(v.x, v.x, fmaf(v.y, v.y, fmaf(v.z, v.z, v.w * v.w)));
#pragma unroll
  for (int o = 32; o >= 1; o >>= 1) { s += __shfl_xor(s, o); ss += __shfl_xor(ss, o); }
  __shared__ float sa[8], sb[8];
  int nw = blockDim.x >> 6;
  if ((tid & 63) == 0) { sa[tid >> 6] = s; sb[tid >> 6] = ss; }
  __syncthreads();
  float S = 0.f, SS = 0.f;
  for (int i = 0; i < nw; ++i) { S += sa[i]; SS += sb[i]; }
  float mean = S / (float)D;
  float var = SS / (float)D - mean * mean;
  float inv = rsqrtf(var + 1e-5f);
  float4 wv = ((const float4*)gw)[tid];
  float4 bv = ((const float4*)gb)[tid];
  float o0 = (v.x - mean) * inv * wv.x + bv.x;
  float o1 = (v.y - mean) * inv * wv.y + bv.y;
  float o2 = (v.z - mean) * inv * wv.z + bv.z;
  float o3 = (v.w - mean) * inv * wv.w + bv.w;
  if (BOUT) {
    ushort4 o; o.x = f2bf(o0); o.y = f2bf(o1); o.z = f2bf(o2); o.w = f2bf(o3);
    ((ushort4*)outp)[(size_t)row * (D >> 2) + tid] = o;
  } else {
    float4 o; o.x = o0; o.y = o1; o.z = o2; o.w = o3;
    ((float4*)outp)[(size_t)row * (D >> 2) + tid] = o;
  }
}

// ---------------------------------------------------------------- LN2 column stats
// xdTb bf16 [512][8192] -> meanv[8192], invv[8192].
__global__ __launch_bounds__(256) void ln_stats(
    const u16* __restrict__ xdTb, float* __restrict__ meanv, float* __restrict__ invv) {
  int lane = threadIdx.x & 63;
  int seg = threadIdx.x >> 6;
  int col = blockIdx.x * 64 + lane;
  float s = 0.f, ss = 0.f;
  const u16* p = xdTb + (size_t)(seg * 128) * 8192 + col;
#pragma unroll 8
  for (int r = 0; r < 128; ++r) {
    float v = bf2f(p[(size_t)r * 8192]);
    s += v; ss = fmaf(v, v, ss);
  }
  __shared__ float sa[4][64], sb[4][64];
  sa[seg][lane] = s; sb[seg][lane] = ss;
  __syncthreads();
  if (threadIdx.x < 64) {
    float S = sa[0][lane] + sa[1][lane] + sa[2][lane] + sa[3][lane];
    float SS = sb[0][lane] + sb[1][lane] + sb[2][lane] + sb[3][lane];
    float mean = S * (1.0f / 512.0f);
    float var = SS * (1.0f / 512.0f) - mean * mean;
    meanv[blockIdx.x * 64 + lane] = mean;
    invv[blockIdx.x * 64 + lane] = rsqrtf(var + 1e-5f);
  }
}

// ---------------------------------------------------------------- unified 128x128 GEMM
// C[M,N] = A[M,K] @ Bt[N,K]^T, 4 waves (2x2), BK=64, double-buffered 64 KiB LDS
// (2 blocks/CU), 2-phase schedule, XOR slot swizzle, LDS-shuffle epilogue.
// MODE 1: bf16 out   2: bf16(C*aux)   3: f32 C+bias[n]+res[m,n]
template <int MODE>
__global__ __launch_bounds__(256, 2) void gemm128p(
    const u16* __restrict__ A, const u16* __restrict__ Bt,
    int M, int N, int K,
    float* Cf, u16* Cb, const u16* aux,
    const float* __restrict__ bias, const float* __restrict__ res) {
  constexpr int BUF = 16384;  // u16 per buffer: A 128x64 + B 128x64
  __shared__ __align__(16) u16 lds[2 * BUF];
  const int tid = threadIdx.x;
  const int lane = tid & 63;
  const int w = tid >> 6;  // 0..3
  const int nwg = (int)gridDim.x;
  const int cpx = nwg >> 3;
  const int bid = (nwg & 7) ? (int)blockIdx.x
                            : ((int)blockIdx.x & 7) * cpx + ((int)blockIdx.x >> 3);
  const int tiles_n = N >> 7;
  const int tm = (bid / tiles_n) << 7;
  const int tn = (bid % tiles_n) << 7;

  const int wm = w >> 1, wn = w & 1;
  const int lr = lane & 15;
  const int kq = lane >> 4;
  const int l7 = lane & 7;
  const int rsub = lane >> 3;
  const int sslot = (lane & 7) ^ rsub;  // pre-swizzled source slot
  const u16* gA = A + (size_t)(tm + w * 32 + rsub) * K + sslot * 8;
  const u16* gB = Bt + (size_t)(tn + w * 32 + rsub) * K + sslot * 8;
  auto ldsc = (__attribute__((address_space(3))) char*)lds;

  auto STAGE = [&](int kt, int c) {
    const size_t kof = (size_t)kt << 6;
#pragma unroll
    for (int i = 0; i < 4; ++i) {
      u32 da = (u32)(c * BUF + (w * 32 + i * 8) * 64) * 2u;
      __builtin_amdgcn_global_load_lds(
          (const __attribute__((address_space(1))) void*)(gA + (size_t)(i * 8) * K + kof),
          (__attribute__((address_space(3))) void*)(ldsc + da), 16, 0, 0);
      __builtin_amdgcn_global_load_lds(
          (const __attribute__((address_space(1))) void*)(gB + (size_t)(i * 8) * K + kof),
          (__attribute__((address_space(3))) void*)(ldsc + da + 16384), 16, 0, 0);
    }
  };

  f32x4 acc[4][4] = {};
  const int NT = K >> 6;

  STAGE(0, 0);
  asm volatile("s_waitcnt vmcnt(0)" ::: "memory");
  __builtin_amdgcn_s_barrier();
  __builtin_amdgcn_sched_barrier(0);

  int cur = 0;
  for (int kt = 0; kt < NT; ++kt) {
    if (kt + 1 < NT) STAGE(kt + 1, cur ^ 1);  // issue-early: hides under MFMA
    const u32 ab = (u32)cur * BUF;
#pragma unroll
    for (int ks = 0; ks < 2; ++ks) {
      const int slp = ((((ks << 2) | kq)) ^ l7) << 3;
      bf16x8 af[4], bv[4];
#pragma unroll
      for (int mi = 0; mi < 4; ++mi) {
        int ra = wm * 64 + mi * 16 + lr;
        af[mi] = *(const bf16x8*)&lds[ab + ra * 64 + slp];
      }
#pragma unroll
      for (int ni = 0; ni < 4; ++ni) {
        int rb = wn * 64 + ni * 16 + lr;
        bv[ni] = *(const bf16x8*)&lds[ab + 8192 + rb * 64 + slp];
      }
      __builtin_amdgcn_s_setprio(1);
#pragma unroll
      for (int mi = 0; mi < 4; ++mi)
#pragma unroll
        for (int ni = 0; ni < 4; ++ni)
          acc[mi][ni] = __builtin_amdgcn_mfma_f32_16x16x32_bf16(af[mi], bv[ni], acc[mi][ni], 0, 0, 0);
      __builtin_amdgcn_s_setprio(0);
    }
    asm volatile("s_waitcnt vmcnt(0)" ::: "memory");
    __builtin_amdgcn_s_barrier();
    __builtin_amdgcn_sched_barrier(0);
    cur ^= 1;
  }

  // ---- LDS-shuffle epilogue (wave-local; per-wave scratch [16][68] f32)
  float* lf = (float*)lds + w * (16 * 68);
  const int er = lane >> 2;          // output row within 16-row slab
  const int ec = (lane & 3) << 4;    // col chunk base (0/16/32/48)
  const int gcol = tn + wn * 64 + ec;
#pragma unroll
  for (int mi = 0; mi < 4; ++mi) {
#pragma unroll
    for (int ni = 0; ni < 4; ++ni)
#pragma unroll
      for (int j = 0; j < 4; ++j)
        lf[(kq * 4 + j) * 68 + ni * 16 + lr] = acc[mi][ni][j];
    float v[16];
#pragma unroll
    for (int q = 0; q < 4; ++q)
      *(float4*)&v[q * 4] = *(const float4*)&lf[er * 68 + ec + q * 4];
    const int gr = tm + wm * 64 + mi * 16 + er;
    if (MODE == 3) {
      const float* rr = res + (size_t)gr * N + gcol;
      const float* br = bias + gcol;
      float* orr = Cf + (size_t)gr * N + gcol;
#pragma unroll
      for (int q = 0; q < 4; ++q) {
        float4 rv = *(const float4*)(rr + q * 4);
        float4 bv4 = *(const float4*)(br + q * 4);
        float4 ov;
        ov.x = v[q * 4 + 0] + bv4.x + rv.x;
        ov.y = v[q * 4 + 1] + bv4.y + rv.y;
        ov.z = v[q * 4 + 2] + bv4.z + rv.z;
        ov.w = v[q * 4 + 3] + bv4.w + rv.w;
        *(float4*)(orr + q * 4) = ov;
      }
    } else {
      u32 pk[8];
      if (MODE == 2) {
        const u16* ar = aux + (size_t)gr * N + gcol;
        uint4 a0 = *(const uint4*)ar;
        uint4 a1 = *(const uint4*)(ar + 8);
        u32 aw[8] = {a0.x, a0.y, a0.z, a0.w, a1.x, a1.y, a1.z, a1.w};
#pragma unroll
        for (int e = 0; e < 8; ++e) {
          float m0 = v[2 * e] * bf2f((u16)(aw[e] & 0xffffu));
          float m1 = v[2 * e + 1] * bf2f((u16)(aw[e] >> 16));
          pk[e] = (u32)f2bf(m0) | ((u32)f2bf(m1) << 16);
        }
      } else {
#pragma unroll
        for (int e = 0; e < 8; ++e)
          pk[e] = (u32)f2bf(v[2 * e]) | ((u32)f2bf(v[2 * e + 1]) << 16);
      }
      u16* orr = Cb + (size_t)gr * N + gcol;
      uint4 s0 = {pk[0], pk[1], pk[2], pk[3]};
      uint4 s1 = {pk[4], pk[5], pk[6], pk[7]};
      *(uint4*)orr = s0;
      *(uint4*)(orr + 8) = s1;
    }
  }
}

// ---------------------------------------------------------------- DSS kernel generation
__global__ __launch_bounds__(256) void kgen_s(
    const float* __restrict__ LR, const float* __restrict__ LI, u16* __restrict__ SRSI) {
  int idx0 = blockIdx.x * 256 + threadIdx.x;
  int l = idx0 >> 10;
  int kk = idx0 & 1023;
  int n = kk & 511;
  double a = exp((double)LR[n]);
  double om = exp((double)LI[n]);
  double ld = (double)l;
  float decay = (float)exp(-a * ld);
  double th = fmod(om * ld, 6.283185307179586477);
  float c, s;
  sincosf((float)th, &s, &c);
  SRSI[idx0] = f2bf(decay * ((kk < 512) ? c : s));
}

__global__ __launch_bounds__(256) void kgen_c(
    const float* __restrict__ LR, const float* __restrict__ LI,
    const float* __restrict__ CR, const float* __restrict__ CI, u16* __restrict__ Ct) {
  int idx0 = blockIdx.x * 256 + threadIdx.x;  // over 512*512
  int h = idx0 >> 9, n = idx0 & 511;
  float eLR = expf(LR[n]), eLI = expf(LI[n]);
  float lre = -eLR, lim = eLI;
  float er = expf(lre);
  float c, s;
  sincosf(lim, &s, &c);
  float wr = er * c - 1.0f, wi = er * s;
  float den = lre * lre + lim * lim;
  float gr = (wr * lre + wi * lim) / den;
  float gi = (wi * lre - wr * lim) / den;
  float cr = CR[(size_t)h * 512 + n], ci = CI[(size_t)h * 512 + n];
  float ccr = cr * gr - ci * gi;
  float cci = cr * gi + ci * gr;
  Ct[(size_t)h * 1024 + n] = f2bf(ccr);
  Ct[(size_t)h * 1024 + 512 + n] = f2bf(-cci);
}

// ---------------------------------------------------------------- twiddle table
__global__ __launch_bounds__(256) void twfill(float4* __restrict__ twg4) {
  int j = blockIdx.x * 256 + threadIdx.x;
  float t1 = -6.2831853071795864769f * (float)j / 8192.0f;
  float s1, c1, s2, c2;
  sincosf(t1, &s1, &c1);
  sincosf(2.0f * t1, &s2, &c2);
  twg4[j] = {c1, s1, c2, s2};
}

// ---------------------------------------------------------------- FFT machinery
struct C2 { float x, y; };
__device__ __forceinline__ C2 cadd(C2 a, C2 b) { return {a.x + b.x, a.y + b.y}; }
__device__ __forceinline__ C2 csub(C2 a, C2 b) { return {a.x - b.x, a.y - b.y}; }
__device__ __forceinline__ C2 cmul(C2 a, C2 b) {
  return {a.x * b.x - a.y * b.y, a.x * b.y + a.y * b.x};
}
__device__ __forceinline__ C2 cmulni(C2 a) { return {a.y, -a.x}; }  // * (-i)

__device__ __forceinline__ int swz(int a) {
  return a ^ ((a >> 7) & 15) ^ ((a >> 11) & 3) ^ ((a >> 2) & 8) ^ ((a >> 3) & 2) ^ ((a >> 4) & 4);
}

#define BR13(x) ((int)(__brev((u32)(x)) >> 19))
#define RS 0.70710678118654752f

__device__ __forceinline__ void dif_pass11z(C2* z, int tid, const float4* __restrict__ twg4) {
#pragma unroll
  for (int j = 0; j < 4; ++j) {
    int i0 = tid + j * 512;
    int ia = swz(i0), ib = swz(i0 + 2048), ic = swz(i0 + 4096), id = swz(i0 + 6144);
    C2 a = z[ia], bb = z[ib];
    float4 wv = twg4[i0];
    C2 w = {wv.x, wv.y};
    C2 wm = {wv.y, -wv.x};
    C2 w2 = {wv.z, wv.w};
    C2 aw = cmul(a, w);
    C2 bw = cmul(bb, wm);
    z[ia] = cadd(a, bb);
    z[ib] = cmul(csub(a, bb), w2);
    z[ic] = cadd(aw, bw);
    z[id] = cmul(csub(aw, bw), w2);
  }
}

template <int LOGM>
__device__ __forceinline__ void dif_pass(C2* z, int tid, const float4* __restrict__ twg4) {
  const int M4 = 1 << LOGM;
#pragma unroll
  for (int j = 0; j < 4; ++j) {
    int b = tid + j * 512;
    int pos = b & (M4 - 1);
    int i0 = ((b >> LOGM) << (LOGM + 2)) | pos;
    int ia = swz(i0), ib = swz(i0 + M4), ic = swz(i0 + 2 * M4), id = swz(i0 + 3 * M4);
    C2 a = z[ia], bb = z[ib], c = z[ic], d = z[id];
    float4 wv = twg4[pos << (11 - LOGM)];
    C2 w = {wv.x, wv.y};
    C2 wm = {wv.y, -wv.x};
    C2 w2 = {wv.z, wv.w};
    C2 a1 = cadd(a, c);
    C2 c1 = cmul(csub(a, c), w);
    C2 b1 = cadd(bb, d);
    C2 d1 = cmul(csub(bb, d), wm);
    z[ia] = cadd(a1, b1);
    z[ib] = cmul(csub(a1, b1), w2);
    z[ic] = cadd(c1, d1);
    z[id] = cmul(csub(c1, d1), w2);
  }
}

template <int LOGM>
__device__ __forceinline__ void dit_pass(C2* z, int tid, const float4* __restrict__ twg4) {
  const int M4 = 1 << LOGM;
#pragma unroll
  for (int j = 0; j < 4; ++j) {
    int b = tid + j * 512;
    int pos = b & (M4 - 1);
    int i0 = ((b >> LOGM) << (LOGM + 2)) | pos;
    int ia = swz(i0), ib = swz(i0 + M4), ic = swz(i0 + 2 * M4), id = swz(i0 + 3 * M4);
    C2 a = z[ia], bb = z[ib], c = z[ic], d = z[id];
    float4 wv = twg4[pos << (11 - LOGM)];
    C2 w = {wv.x, wv.y};
    C2 wm = {wv.y, -wv.x};
    C2 wa = {wv.z, wv.w};
    C2 t = cmul(wa, bb);
    C2 a1 = cadd(a, t), b1 = csub(a, t);
    C2 u = cmul(wa, d);
    C2 c1 = cadd(c, u), d1 = csub(c, u);
    C2 v = cmul(w, c1);
    C2 xx = cmul(wm, d1);
    z[ia] = cadd(a1, v);
    z[ic] = csub(a1, v);
    z[ib] = cadd(b1, xx);
    z[id] = csub(b1, xx);
  }
}

__device__ __forceinline__ void dit_pass11_last(C2* z, int tid, const float4* __restrict__ twg4) {
#pragma unroll
  for (int j = 0; j < 4; ++j) {
    int i0 = tid + j * 512;
    int ia = swz(i0), ib = swz(i0 + 2048), ic = swz(i0 + 4096), id = swz(i0 + 6144);
    C2 a = z[ia], bb = z[ib], c = z[ic], d = z[id];
    float4 wv = twg4[i0];
    C2 w = {wv.x, wv.y};
    C2 wm = {wv.y, -wv.x};
    C2 wa = {wv.z, wv.w};
    C2 t = cmul(wa, bb);
    C2 a1 = cadd(a, t), b1 = csub(a, t);
    C2 u = cmul(wa, d);
    C2 c1 = cadd(c, u), d1 = csub(c, u);
    z[ia] = cadd(a1, cmul(w, c1));
    z[ib] = cadd(b1, cmul(wm, d1));
  }
}

__device__ __forceinline__ void dif_r8(C2* z, int tid) {
#pragma unroll
  for (int j = 0; j < 2; ++j) {
    int base = (tid + j * 512) << 3;
    int ad[8]; C2 x[8];
#pragma unroll
    for (int e = 0; e < 8; ++e) { ad[e] = swz(base + e); x[e] = z[ad[e]]; }
    C2 t;
    t = csub(x[0], x[4]); x[0] = cadd(x[0], x[4]); x[4] = t;
    t = csub(x[1], x[5]); x[1] = cadd(x[1], x[5]); x[5] = cmul(t, {RS, -RS});
    t = csub(x[2], x[6]); x[2] = cadd(x[2], x[6]); x[6] = cmulni(t);
    t = csub(x[3], x[7]); x[3] = cadd(x[3], x[7]); x[7] = cmul(t, {-RS, -RS});
    t = csub(x[0], x[2]); x[0] = cadd(x[0], x[2]); x[2] = t;
    t = csub(x[1], x[3]); x[1] = cadd(x[1], x[3]); x[3] = cmulni(t);
    t = csub(x[4], x[6]); x[4] = cadd(x[4], x[6]); x[6] = t;
    t = csub(x[5], x[7]); x[5] = cadd(x[5], x[7]); x[7] = cmulni(t);
    t = csub(x[0], x[1]); x[0] = cadd(x[0], x[1]); x[1] = t;
    t = csub(x[2], x[3]); x[2] = cadd(x[2], x[3]); x[3] = t;
    t = csub(x[4], x[5]); x[4] = cadd(x[4], x[5]); x[5] = t;
    t = csub(x[6], x[7]); x[6] = cadd(x[6], x[7]); x[7] = t;
#pragma unroll
    for (int e = 0; e < 8; ++e) z[ad[e]] = x[e];
  }
}

__device__ __forceinline__ void r8_fused(C2* z, int tid, const u32* __restrict__ kfr) {
#pragma unroll
  for (int j = 0; j < 2; ++j) {
    int base = (tid + j * 512) << 3;
    int ad[8]; C2 x[8];
#pragma unroll
    for (int e = 0; e < 8; ++e) { ad[e] = swz(base + e); x[e] = z[ad[e]]; }
    uint4 k0 = *(const uint4*)(kfr + base);
    uint4 k1 = *(const uint4*)(kfr + base + 4);
    u32 kw[8] = {k0.x, k0.y, k0.z, k0.w, k1.x, k1.y, k1.z, k1.w};
    C2 t;
    t = csub(x[0], x[4]); x[0] = cadd(x[0], x[4]); x[4] = t;
    t = csub(x[1], x[5]); x[1] = cadd(x[1], x[5]); x[5] = cmul(t, {RS, -RS});
    t = csub(x[2], x[6]); x[2] = cadd(x[2], x[6]); x[6] = cmulni(t);
    t = csub(x[3], x[7]); x[3] = cadd(x[3], x[7]); x[7] = cmul(t, {-RS, -RS});
    t = csub(x[0], x[2]); x[0] = cadd(x[0], x[2]); x[2] = t;
    t = csub(x[1], x[3]); x[1] = cadd(x[1], x[3]); x[3] = cmulni(t);
    t = csub(x[4], x[6]); x[4] = cadd(x[4], x[6]); x[6] = t;
    t = csub(x[5], x[7]); x[5] = cadd(x[5], x[7]); x[7] = cmulni(t);
    t = csub(x[0], x[1]); x[0] = cadd(x[0], x[1]); x[1] = t;
    t = csub(x[2], x[3]); x[2] = cadd(x[2], x[3]); x[3] = t;
    t = csub(x[4], x[5]); x[4] = cadd(x[4], x[5]); x[5] = t;
    t = csub(x[6], x[7]); x[6] = cadd(x[6], x[7]); x[7] = t;
#pragma unroll
    for (int e = 0; e < 8; ++e) {
      C2 kf = {bf2f((u16)(kw[e] & 0xffffu)), bf2f((u16)(kw[e] >> 16))};
      C2 pr = cmul(x[e], kf);
      x[e] = {pr.x, -pr.y};
    }
    t = x[1]; x[1] = csub(x[0], t); x[0] = cadd(x[0], t);
    t = x[3]; x[3] = csub(x[2], t); x[2] = cadd(x[2], t);
    t = x[5]; x[5] = csub(x[4], t); x[4] = cadd(x[4], t);
    t = x[7]; x[7] = csub(x[6], t); x[6] = cadd(x[6], t);
    t = x[2];          x[2] = csub(x[0], t); x[0] = cadd(x[0], t);
    t = cmulni(x[3]);  x[3] = csub(x[1], t); x[1] = cadd(x[1], t);
    t = x[6];          x[6] = csub(x[4], t); x[4] = cadd(x[4], t);
    t = cmulni(x[7]);  x[7] = csub(x[5], t); x[5] = cadd(x[5], t);
    t = x[4];                    x[4] = csub(x[0], t); x[0] = cadd(x[0], t);
    t = cmul(x[5], {RS, -RS});   x[5] = csub(x[1], t); x[1] = cadd(x[1], t);
    t = cmulni(x[6]);            x[6] = csub(x[2], t); x[2] = cadd(x[2], t);
    t = cmul(x[7], {-RS, -RS});  x[7] = csub(x[3], t); x[3] = cadd(x[3], t);
#pragma unroll
    for (int e = 0; e < 8; ++e) z[ad[e]] = x[e];
  }
}

// ---------------------------------------------------------------- K-spectrum kernel
// Block g: FFT(K[2g] + i*K[2g+1]) from bf16 K^T rows, Hermitian split, store
// bit-rev bf16-packed spectra.
__global__ __launch_bounds__(512) void kfft(
    const u16* __restrict__ KTb, const float4* __restrict__ twg4,
    u32* __restrict__ Kfb) {
  __shared__ C2 z[8192];
  const int g = blockIdx.x;
  const int tid = threadIdx.x;
  const u16* k0r = KTb + ((size_t)(2 * g) << 12);
  const u16* k1r = KTb + ((size_t)(2 * g + 1) << 12);
  const int l0 = tid << 3;
  uint4 ka = *(const uint4*)(k0r + l0);
  uint4 kb = *(const uint4*)(k1r + l0);
  u32 kaw[4] = {ka.x, ka.y, ka.z, ka.w};
  u32 kbw[4] = {kb.x, kb.y, kb.z, kb.w};
#pragma unroll
  for (int e = 0; e < 8; ++e) {
    float a0 = bf2f((u16)((kaw[e >> 1] >> ((e & 1) * 16)) & 0xffffu));
    float a1 = bf2f((u16)((kbw[e >> 1] >> ((e & 1) * 16)) & 0xffffu));
    z[swz(l0 + e)] = {a0, a1};
  }
  __syncthreads();

  dif_pass11z(z, tid, twg4); __syncthreads();
  dif_pass<9>(z, tid, twg4); __syncthreads();
  dif_pass<7>(z, tid, twg4); __syncthreads();
  dif_pass<5>(z, tid, twg4); __syncthreads();
  dif_pass<3>(z, tid, twg4); __syncthreads();
  dif_r8(z, tid);            __syncthreads();

  u32* o0 = Kfb + ((size_t)(2 * g) << 13);
  u32* o1 = Kfb + ((size_t)(2 * g + 1) << 13);
#pragma unroll
  for (int it = 0; it < 16; ++it) {
    int p = tid + it * 512;
    int k = BR13(p);
    int km = (8192 - k) & 8191;
    int p2 = BR13(km);
    C2 Zk = z[swz(p)], Zm = z[swz(p2)];
    float f0r = 0.5f * (Zk.x + Zm.x), f0i = 0.5f * (Zk.y - Zm.y);
    float f1r = 0.5f * (Zk.y + Zm.y), f1i = 0.5f * (Zm.x - Zk.x);
    o0[p] = (u32)f2bf(f0r) | ((u32)f2bf(f0i) << 16);
    o1[p] = (u32)f2bf(f1r) | ((u32)f2bf(f1i) << 16);
  }
}

// ---------------------------------------------------------------- main FFT conv
__global__ __launch_bounds__(512) void fft_conv3(
    const u16* __restrict__ xdTb, const u32* __restrict__ Kfb,
    const float* __restrict__ meanv, const float* __restrict__ invv,
    const float* __restrict__ n2w, const float* __restrict__ n2b,
    const float* __restrict__ Dv, const float4* __restrict__ twg4,
    u16* __restrict__ dT) {
  __shared__ C2 z[8192];
  const int h = blockIdx.x;
  const int tid = threadIdx.x;
  const u16* xr = xdTb + ((size_t)h << 13);
  const float w2h = n2w[h], b2h = n2b[h], Dh = Dv[h];
  const int l0 = tid << 3;

  float mv[8], iv[8], xn0[8], xn1[8];
  uint4 xa = *(const uint4*)(xr + l0);
  u32 xw[4] = {xa.x, xa.y, xa.z, xa.w};
  *(float4*)&mv[0] = *(const float4*)(meanv + l0);
  *(float4*)&mv[4] = *(const float4*)(meanv + l0 + 4);
  *(float4*)&iv[0] = *(const float4*)(invv + l0);
  *(float4*)&iv[4] = *(const float4*)(invv + l0 + 4);
#pragma unroll
  for (int e = 0; e < 8; ++e) {
    float x = bf2f((u16)((xw[e >> 1] >> ((e & 1) * 16)) & 0xffffu));
    xn0[e] = (x - mv[e]) * iv[e] * w2h + b2h;
  }
  xa = *(const uint4*)(xr + 4096 + l0);
  xw[0] = xa.x; xw[1] = xa.y; xw[2] = xa.z; xw[3] = xa.w;
  *(float4*)&mv[0] = *(const float4*)(meanv + 4096 + l0);
  *(float4*)&mv[4] = *(const float4*)(meanv + 4096 + l0 + 4);
  *(float4*)&iv[0] = *(const float4*)(invv + 4096 + l0);
  *(float4*)&iv[4] = *(const float4*)(invv + 4096 + l0 + 4);
#pragma unroll
  for (int e = 0; e < 8; ++e) {
    float x = bf2f((u16)((xw[e >> 1] >> ((e & 1) * 16)) & 0xffffu));
    xn1[e] = (x - mv[e]) * iv[e] * w2h + b2h;
  }
#pragma unroll
  for (int e = 0; e < 8; ++e) z[swz(l0 + e)] = {xn0[e], xn1[e]};
  __syncthreads();

  dif_pass11z(z, tid, twg4); __syncthreads();
  dif_pass<9>(z, tid, twg4); __syncthreads();
  dif_pass<7>(z, tid, twg4); __syncthreads();
  dif_pass<5>(z, tid, twg4); __syncthreads();
  dif_pass<3>(z, tid, twg4); __syncthreads();
  r8_fused(z, tid, Kfb + ((size_t)h << 13)); __syncthreads();
  dit_pass<3>(z, tid, twg4); __syncthreads();
  dit_pass<5>(z, tid, twg4); __syncthreads();
  dit_pass<7>(z, tid, twg4); __syncthreads();
  dit_pass<9>(z, tid, twg4); __syncthreads();
  dit_pass11_last(z, tid, twg4); __syncthreads();

  const float sc = 1.0f / 8192.0f;
  u16 o0[8], o1[8];
#pragma unroll
  for (int e = 0; e < 8; ++e) {
    C2 v = z[swz(l0 + e)];
    o0[e] = f2bf(fmaf(Dh, xn0[e], v.x * sc));
    o1[e] = f2bf(fmaf(Dh, xn1[e], -v.y * sc));
  }
  uint4 p0, p1;
  p0.x = (u32)o0[0] | ((u32)o0[1] << 16);
  p0.y = (u32)o0[2] | ((u32)o0[3] << 16);
  p0.z = (u32)o0[4] | ((u32)o0[5] << 16);
  p0.w = (u32)o0[6] | ((u32)o0[7] << 16);
  p1.x = (u32)o1[0] | ((u32)o1[1] << 16);
  p1.y = (u32)o1[2] | ((u32)o1[3] << 16);
  p1.z = (u32)o1[4] | ((u32)o1[5] << 16);
  p1.w = (u32)o1[6] | ((u32)o1[7] << 16);
  *(uint4*)(dT + ((size_t)h << 13) + l0) = p0;
  *(uint4*)(dT + ((size_t)h << 13) + 4096 + l0) = p1;
}

// ---------------------------------------------------------------- launch
extern "C" void kernel_launch(void* const* d_in, const int* in_sizes, int n_in,
                              void* d_out, int out_size, void* d_ws, size_t ws_size,
                              hipStream_t stream) {
  (void)in_sizes; (void)n_in; (void)out_size; (void)ws_size;
  const float* idx  = (const float*)d_in[0];
  const float* n1w  = (const float*)d_in[1];
  const float* n1b  = (const float*)d_in[2];
  const float* Wxg  = (const float*)d_in[3];
  const float* Wdin = (const float*)d_in[4];
  const float* n2w  = (const float*)d_in[5];
  const float* n2b  = (const float*)d_in[6];
  const float* LR   = (const float*)d_in[7];
  const float* LI   = (const float*)d_in[8];
  const float* CR   = (const float*)d_in[9];
  const float* CI   = (const float*)d_in[10];
  const float* Dv   = (const float*)d_in[11];
  const float* Wgate= (const float*)d_in[12];
  const float* Wout = (const float*)d_in[13];
  const float* bout = (const float*)d_in[14];
  float* out = (float*)d_out;

  const int Bn = 2, L = 4096, DIM = 1024, HID = 4096, H = 512;
  const int M = Bn * L;  // 8192

  char* p = (char*)d_ws;
  auto alloc = [&](size_t bytes) { char* q = p; p += (bytes + 255) & ~(size_t)255; return q; };
  u16* Wxg_t   = (u16*)alloc((size_t)HID * DIM * 2);
  u16* Wdin_t  = (u16*)alloc((size_t)H * DIM * 2);
  u16* Wgate_t = (u16*)alloc((size_t)HID * H * 2);
  u16* Wout_t  = (u16*)alloc((size_t)DIM * HID * 2);
  u16* xbf     = (u16*)alloc((size_t)M * DIM * 2);    // 16 MB; reused as Kfb later
  u16* xg      = (u16*)alloc((size_t)M * HID * 2);    // later aliased as e
  u16* xdTb    = (u16*)alloc((size_t)H * M * 2);      // bf16 [512][8192]
  float* meanv = (float*)alloc((size_t)M * 4);
  float* invv  = (float*)alloc((size_t)M * 4);
  u16* SRSI    = (u16*)alloc((size_t)L * 1024 * 2);
  u16* Ct      = (u16*)alloc((size_t)H * 1024 * 2);
  u16* KTb     = (u16*)alloc((size_t)H * L * 2);      // bf16 [512][4096]
  u16* dTm     = (u16*)alloc((size_t)H * M * 2);      // d^T [512][8192]
  u16* dbuf    = (u16*)alloc((size_t)M * H * 2);      // d   [8192][512]
  float4* twg4 = (float4*)alloc((size_t)2048 * 16);
  u32* Kfb = (u32*)xbf;  // [512][8192] u32 (bf16 pair); xbf dead after step 4

  // 1) weight transpose+convert + twiddle table
  trans_conv<<<dim3((DIM / 32) * (HID / 32)), 256, 0, stream>>>(Wxg, Wxg_t, DIM, HID);
  trans_conv<<<dim3((DIM / 32) * (H / 32)), 256, 0, stream>>>(Wdin, Wdin_t, DIM, H);
  trans_conv<<<dim3((H / 32) * (HID / 32)), 256, 0, stream>>>(Wgate, Wgate_t, H, HID);
  trans_conv<<<dim3((HID / 32) * (DIM / 32)), 256, 0, stream>>>(Wout, Wout_t, HID, DIM);
  twfill<<<dim3(8), 256, 0, stream>>>(twg4);
  // 2) LN1
  ln_kernel<true><<<dim3(M), 256, 0, stream>>>(idx, n1w, n1b, xbf, DIM);
  // 3) xg = x @ Wxg (bf16), grid 2048
  gemm128p<1><<<dim3((M / 128) * (HID / 128)), 256, 0, stream>>>(
      xbf, Wxg_t, M, HID, DIM, nullptr, xg, nullptr, nullptr, nullptr);
  // 4) xd^T = Wdin_t @ xbf^T  bf16 [512][8192], grid 256
  gemm128p<1><<<dim3((H / 128) * (M / 128)), 256, 0, stream>>>(
      Wdin_t, xbf, H, M, DIM, nullptr, xdTb, nullptr, nullptr, nullptr);
  // 5) LN2 column stats (from bf16)
  ln_stats<<<dim3(M / 64), 256, 0, stream>>>(xdTb, meanv, invv);
  // 6) S and C generation
  kgen_s<<<dim3(L * 1024 / 256), 256, 0, stream>>>(LR, LI, SRSI);
  kgen_c<<<dim3(H * 512 / 256), 256, 0, stream>>>(LR, LI, CR, CI, Ct);
  // 7) K^T = Ct @ SRSI^T  bf16 [512][4096], grid 128
  gemm128p<1><<<dim3((H / 128) * (L / 128)), 256, 0, stream>>>(
      Ct, SRSI, H, L, 1024, nullptr, KTb, nullptr, nullptr, nullptr);
  // 7b) Kf spectra (bit-rev bf16), 256 blocks
  kfft<<<dim3(H / 2), 512, 0, stream>>>(KTb, twg4, Kfb);
  // 8) packed FFT conv -> d^T bf16, 512 blocks
  fft_conv3<<<dim3(H), 512, 0, stream>>>(xdTb, Kfb, meanv, invv, n2w, n2b, Dv, twg4, dTm);
  // 8b) d^T -> d
  trans_bf<<<dim3((H / 32) * (M / 32)), 256, 0, stream>>>(dTm, dbuf, H, M);
  // 9) e = (d @ Wgate) * xg  (bf16, aliases xg), grid 2048
  gemm128p<2><<<dim3((M / 128) * (HID / 128)), 256, 0, stream>>>(
      dbuf, Wgate_t, M, HID, H, nullptr, xg, xg, nullptr, nullptr);
  // 10) out = e @ Wout + bout + idx (f32), grid 512
  gemm128p<3><<<dim3((M / 128) * (DIM / 128)), 256, 0, stream>>>(
      xg, Wout_t, M, DIM, HID, out, nullptr, nullptr, bout, idx);
}